// Round 1
// baseline (1553.230 us; speedup 1.0000x reference)
//
#include <hip/hip_runtime.h>
#include <cmath>

#define S_LEN 2048
#define DMODEL 1024
#define NHEADS 16
#define DK 64
#define BATCH 2
#define MTOT (BATCH * S_LEN) /* 4096 */

// ---------------------------------------------------------------------------
// RoPE tables: ct/st[si*32 + i] = cos/sin(pos[si] * 10000^(-2i/64))
// ---------------------------------------------------------------------------
__global__ void rope_tables_k(const int* __restrict__ tokpos,
                              float* __restrict__ ct, float* __restrict__ st) {
    int idx = blockIdx.x * blockDim.x + threadIdx.x;  // 0 .. 2048*32-1
    int si = idx >> 5;
    int ip = idx & 31;
    float pos = (float)tokpos[si];
    float inv_freq = powf(10000.0f, -(float)(2 * ip) / 64.0f);
    float ang = pos * inv_freq;
    ct[idx] = cosf(ang);
    st[idx] = sinf(ang);
}

// ---------------------------------------------------------------------------
// C[4096,1024] = A[4096,1024] @ W[1024,1024], optional fused RoPE epilogue.
// grid: (N/128, M/128, nz). z selects W/C; bit z of ropeMask enables RoPE.
// Block 256 threads (16x16), 8x8 micro-tile, BK=16.
// ---------------------------------------------------------------------------
constexpr int BM = 128, BN = 128, BK = 16;

__global__ __launch_bounds__(256) void gemm3_k(
    const float* __restrict__ A,
    const float* __restrict__ W0, const float* __restrict__ W1,
    const float* __restrict__ W2,
    float* C0, float* C1, float* C2,
    const float* __restrict__ ct, const float* __restrict__ st, int ropeMask) {
    __shared__ float As[BK][BM + 4];  // +4 keeps float4 alignment, breaks conflicts
    __shared__ float Bs[BK][BN];

    const int z = blockIdx.z;
    const float* W = (z == 0) ? W0 : ((z == 1) ? W1 : W2);
    float* C = (z == 0) ? C0 : ((z == 1) ? C1 : C2);
    const bool rope = ((ropeMask >> z) & 1) != 0;

    const int tid = threadIdx.x;
    const int tx = tid & 15;
    const int ty = tid >> 4;
    const int m0 = blockIdx.y * BM;
    const int n0 = blockIdx.x * BN;

    float acc[8][8];
#pragma unroll
    for (int i = 0; i < 8; i++)
#pragma unroll
        for (int j = 0; j < 8; j++) acc[i][j] = 0.f;

    for (int k0 = 0; k0 < DMODEL; k0 += BK) {
        // A tile -> As[k][m] (transposed in LDS)
#pragma unroll
        for (int r = 0; r < 8; r++) {
            int m = (tid >> 4) + r * 16;
            int k = tid & 15;
            As[k][m] = A[(size_t)(m0 + m) * DMODEL + k0 + k];
        }
        // W tile -> Bs[k][n]
#pragma unroll
        for (int r = 0; r < 8; r++) {
            int k = (tid >> 7) + r * 2;
            int n = tid & 127;
            Bs[k][n] = W[(size_t)(k0 + k) * DMODEL + n0 + n];
        }
        __syncthreads();
#pragma unroll
        for (int k = 0; k < BK; k++) {
            float4 a0 = *(const float4*)&As[k][ty * 8];
            float4 a1 = *(const float4*)&As[k][ty * 8 + 4];
            float4 b0 = *(const float4*)&Bs[k][tx * 8];
            float4 b1 = *(const float4*)&Bs[k][tx * 8 + 4];
            float a[8] = {a0.x, a0.y, a0.z, a0.w, a1.x, a1.y, a1.z, a1.w};
            float b[8] = {b0.x, b0.y, b0.z, b0.w, b1.x, b1.y, b1.z, b1.w};
#pragma unroll
            for (int i = 0; i < 8; i++)
#pragma unroll
                for (int j = 0; j < 8; j++) acc[i][j] += a[i] * b[j];
        }
        __syncthreads();
    }

    // epilogue
#pragma unroll
    for (int i = 0; i < 8; i++) {
        int m = m0 + ty * 8 + i;
        float r[8];
        if (rope) {
            int si = m & (S_LEN - 1);
#pragma unroll
            for (int jp = 0; jp < 8; jp += 2) {
                int dh = (n0 + tx * 8 + jp) & 63;  // even dim within head
                int ip = dh >> 1;
                float c = ct[si * 32 + ip];
                float s = st[si * 32 + ip];
                float xe = acc[i][jp], xo = acc[i][jp + 1];
                r[jp] = xe * c - xo * s;
                r[jp + 1] = xe * s + xo * c;
            }
        } else {
#pragma unroll
            for (int j = 0; j < 8; j++) r[j] = acc[i][j];
        }
        float* p = C + (size_t)m * DMODEL + n0 + tx * 8;
        *(float4*)p = make_float4(r[0], r[1], r[2], r[3]);
        *(float4*)(p + 4) = make_float4(r[4], r[5], r[6], r[7]);
    }
}

// ---------------------------------------------------------------------------
// Flash-style causal attention, fp32. One thread per query row.
// grid: (s/256, B*NHEADS). Block 256 threads.
// O may alias Q: each block reads only its own (rows, head) slice of Q into
// registers before writing the identical slice at the end.
// ---------------------------------------------------------------------------
__global__ __launch_bounds__(256) void attn_k(const float* Q,
                                              const float* __restrict__ K,
                                              const float* __restrict__ V,
                                              float* O) {
    __shared__ float Ks[64][64];
    __shared__ float Vs[64][64];
    const int tid = threadIdx.x;
    const int qt = blockIdx.x;
    const int bh = blockIdx.y;
    const int bb = bh >> 4;
    const int h = bh & 15;
    const int q = qt * 256 + tid;

    const float* Qrow = Q + (size_t)(bb * S_LEN + q) * DMODEL + h * DK;
    float qreg[64];
#pragma unroll
    for (int d4 = 0; d4 < 16; d4++) {
        float4 t = ((const float4*)Qrow)[d4];
        qreg[d4 * 4 + 0] = t.x;
        qreg[d4 * 4 + 1] = t.y;
        qreg[d4 * 4 + 2] = t.z;
        qreg[d4 * 4 + 3] = t.w;
    }
    float o[64];
#pragma unroll
    for (int d = 0; d < 64; d++) o[d] = 0.f;
    float mval = -INFINITY, l = 0.f;

    const int ktiles = qt * 4 + 4;  // key tiles of 64 covering keys 0..q_max
    for (int kt = 0; kt < ktiles; kt++) {
        const int kbase = kt * 64;
        __syncthreads();  // previous tile's LDS reads complete
#pragma unroll
        for (int r = 0; r < 4; r++) {
            int fi = tid + r * 256;  // float4 index 0..1023
            int kk = fi >> 4;
            int d = (fi & 15) * 4;
            size_t g = (size_t)(bb * S_LEN + kbase + kk) * DMODEL + h * DK + d;
            *(float4*)&Ks[kk][d] = *(const float4*)(K + g);
            *(float4*)&Vs[kk][d] = *(const float4*)(V + g);
        }
        __syncthreads();
        int kmax = q - kbase + 1;  // causal: keys <= q
        if (kmax > 64) kmax = 64;
        for (int kk = 0; kk < kmax; kk++) {
            float s0 = 0.f, s1 = 0.f, s2 = 0.f, s3 = 0.f;
#pragma unroll
            for (int d4 = 0; d4 < 16; d4++) {
                float4 kv = *(const float4*)&Ks[kk][d4 * 4];
                s0 += qreg[d4 * 4 + 0] * kv.x;
                s1 += qreg[d4 * 4 + 1] * kv.y;
                s2 += qreg[d4 * 4 + 2] * kv.z;
                s3 += qreg[d4 * 4 + 3] * kv.w;
            }
            float sc = (s0 + s1 + s2 + s3) * 0.125f;
            float mnew = fmaxf(mval, sc);
            if (mnew > mval) {
                float scale = __expf(mval - mnew);
                l *= scale;
#pragma unroll
                for (int d = 0; d < 64; d++) o[d] *= scale;
                mval = mnew;
            }
            float p = __expf(sc - mval);
            l += p;
#pragma unroll
            for (int d4 = 0; d4 < 16; d4++) {
                float4 vv = *(const float4*)&Vs[kk][d4 * 4];
                o[d4 * 4 + 0] += p * vv.x;
                o[d4 * 4 + 1] += p * vv.y;
                o[d4 * 4 + 2] += p * vv.z;
                o[d4 * 4 + 3] += p * vv.w;
            }
        }
    }
    float inv = 1.0f / l;
    float* Orow = O + (size_t)(bb * S_LEN + q) * DMODEL + h * DK;
#pragma unroll
    for (int d4 = 0; d4 < 16; d4++) {
        float4 t;
        t.x = o[d4 * 4 + 0] * inv;
        t.y = o[d4 * 4 + 1] * inv;
        t.z = o[d4 * 4 + 2] * inv;
        t.w = o[d4 * 4 + 3] * inv;
        ((float4*)Orow)[d4] = t;
    }
}

// ---------------------------------------------------------------------------
extern "C" void kernel_launch(void* const* d_in, const int* in_sizes, int n_in,
                              void* d_out, int out_size, void* d_ws,
                              size_t ws_size, hipStream_t stream) {
    const float* x = (const float*)d_in[0];
    const float* Wq = (const float*)d_in[1];
    const float* Wk = (const float*)d_in[2];
    const float* Wv = (const float*)d_in[3];
    const float* Wo = (const float*)d_in[4];
    const int* tokpos = (const int*)d_in[5];
    float* out = (float*)d_out;

    const size_t MD = (size_t)MTOT * DMODEL;  // 4096*1024
    float* Q = (float*)d_ws;                  // also attention output (aliased)
    float* K = Q + MD;
    float* V = K + MD;
    float* ct = V + MD;           // 2048*32
    float* st = ct + S_LEN * 32;  // 2048*32

    // 1) RoPE cos/sin tables
    rope_tables_k<<<dim3((S_LEN * 32) / 256), dim3(256), 0, stream>>>(tokpos, ct, st);

    // 2) Q,K,V projections with fused RoPE on Q,K
    gemm3_k<<<dim3(DMODEL / BN, MTOT / BM, 3), dim3(256), 0, stream>>>(
        x, Wq, Wk, Wv, Q, K, V, ct, st, 0x3);

    // 3) causal flash attention; output overwrites Q buffer in-place
    attn_k<<<dim3(S_LEN / 256, BATCH * NHEADS), dim3(256), 0, stream>>>(Q, K, V, Q);

    // 4) output projection
    gemm3_k<<<dim3(DMODEL / BN, MTOT / BM, 1), dim3(256), 0, stream>>>(
        Q, Wo, Wo, Wo, out, out, out, ct, st, 0x0);
}

// Round 2
// 400.594 us; speedup vs baseline: 3.8773x; 3.8773x over previous
//
#include <hip/hip_runtime.h>
#include <cmath>

#define S_LEN 2048
#define DMODEL 1024
#define NHEADS 16
#define DK 64
#define BATCH 2
#define MTOT (BATCH * S_LEN) /* 4096 */

using short8 = __attribute__((ext_vector_type(8))) short;
using floatx4 = __attribute__((ext_vector_type(4))) float;

// float -> bf16 bits, round-to-nearest-even
__device__ __forceinline__ unsigned short f2b(float f) {
    union { float f; unsigned u; } v; v.f = f;
    unsigned r = v.u + 0x7fff + ((v.u >> 16) & 1);
    return (unsigned short)(r >> 16);
}

// async global->LDS, 16 bytes per lane. LDS dest: wave-uniform base + lane*16.
__device__ __forceinline__ void gload16(const void* g, void* l) {
    __builtin_amdgcn_global_load_lds(
        (const __attribute__((address_space(1))) unsigned int*)g,
        (__attribute__((address_space(3))) unsigned int*)l, 16, 0, 0);
}

// ---------------------------------------------------------------------------
// RoPE tables: ct/st[si*32 + ip] = cos/sin(pos[si] * 10000^(-2ip/64))
// ---------------------------------------------------------------------------
__global__ void rope_tables_k(const int* __restrict__ tokpos,
                              float* __restrict__ ct, float* __restrict__ st) {
    int idx = blockIdx.x * blockDim.x + threadIdx.x;
    int si = idx >> 5;
    int ip = idx & 31;
    float pos = (float)tokpos[si];
    float inv_freq = powf(10000.0f, -(float)(2 * ip) / 64.0f);
    float ang = pos * inv_freq;
    ct[idx] = cosf(ang);
    st[idx] = sinf(ang);
}

// ---------------------------------------------------------------------------
// x (fp32) -> xb (bf16), 8 elements/thread
// ---------------------------------------------------------------------------
__global__ __launch_bounds__(256) void cast_x_k(const float* __restrict__ x,
                                                unsigned short* __restrict__ xb) {
    int i = (blockIdx.x * 256 + threadIdx.x) * 8;
    float4 a = *(const float4*)(x + i);
    float4 b = *(const float4*)(x + i + 4);
    short8 o;
    o[0] = f2b(a.x); o[1] = f2b(a.y); o[2] = f2b(a.z); o[3] = f2b(a.w);
    o[4] = f2b(b.x); o[5] = f2b(b.y); o[6] = f2b(b.z); o[7] = f2b(b.w);
    *(short8*)(xb + i) = o;
}

// ---------------------------------------------------------------------------
// W[k][n] fp32 -> Wt[n][k] bf16 (64x64 LDS tile transpose), z selects matrix
// ---------------------------------------------------------------------------
__global__ __launch_bounds__(256) void trans_w_k(
    const float* W0, const float* W1, const float* W2, const float* W3,
    unsigned short* T0, unsigned short* T1, unsigned short* T2, unsigned short* T3) {
    __shared__ float t[64][65];
    int z = blockIdx.z;
    const float* W = z == 0 ? W0 : z == 1 ? W1 : z == 2 ? W2 : W3;
    unsigned short* T = z == 0 ? T0 : z == 1 ? T1 : z == 2 ? T2 : T3;
    int n0 = blockIdx.x * 64, k0 = blockIdx.y * 64;
    int rr = threadIdx.x >> 6, cc = threadIdx.x & 63;
#pragma unroll
    for (int r = 0; r < 16; r++) {
        int row = r * 4 + rr;
        t[row][cc] = W[(size_t)(k0 + row) * DMODEL + n0 + cc];
    }
    __syncthreads();
#pragma unroll
    for (int r = 0; r < 16; r++) {
        int row = r * 4 + rr;
        T[(size_t)(n0 + row) * DMODEL + k0 + cc] = f2b(t[cc][row]);
    }
}

// ---------------------------------------------------------------------------
// bf16 MFMA GEMM: C[4096,1024] = A[4096,1024] x Bt^T  (Bt is [N][K] bf16)
// 128x128 tile, BK=32, 256 thr = 4 waves, each wave 64x64 = 4x4 mfma 16x16x32.
// LDS "fragment blob": chunk c = g*64 + lane holds 16B = row (g*16 + lane&15),
// k-dims (lane>>4)*8..+7; staged with global_load_lds (lane-contiguous dest).
// kind 0: z<2 -> RoPE+bf16 store; z==2 -> transposed bf16 store (Vt).
// kind 1: plain fp32 store.
// ---------------------------------------------------------------------------
__global__ __launch_bounds__(256) void mm_k(
    const unsigned short* __restrict__ A,
    const unsigned short* __restrict__ Bt0, const unsigned short* __restrict__ Bt1,
    const unsigned short* __restrict__ Bt2,
    void* C0, void* C1, void* C2,
    const float* __restrict__ ct, const float* __restrict__ st, int kind) {
    __shared__ __align__(16) unsigned short blob[8192];  // 16 KB: A 8K + B 8K bytes

    const int z = blockIdx.z;
    const unsigned short* Bt = z == 0 ? Bt0 : z == 1 ? Bt1 : Bt2;
    void* C = z == 0 ? C0 : z == 1 ? C1 : C2;
    const int mode = (kind == 1) ? 0 : (z == 2 ? 2 : 1);

    const int tid = threadIdx.x;
    const int w = tid >> 6, lane = tid & 63;
    const int l15 = lane & 15, quad = lane >> 4;
    const int wr = w >> 1, wc = w & 1;
    const int m0 = blockIdx.y * 128, n0 = blockIdx.x * 128;

    floatx4 acc[4][4];
#pragma unroll
    for (int i = 0; i < 4; i++)
#pragma unroll
        for (int j = 0; j < 4; j++) acc[i][j] = (floatx4){0.f, 0.f, 0.f, 0.f};

    for (int k0 = 0; k0 < DMODEL; k0 += 32) {
        if (k0) __syncthreads();
#pragma unroll
        for (int it = 0; it < 4; it++) {
            int g = it * 4 + w;  // wave-uniform group 0..15 (A: 0..7, B: 8..15)
            const unsigned short* gp;
            if (g < 8)
                gp = A + (size_t)(m0 + g * 16 + l15) * DMODEL + k0 + (lane >> 4) * 8;
            else
                gp = Bt + (size_t)(n0 + (g - 8) * 16 + l15) * DMODEL + k0 + (lane >> 4) * 8;
            gload16(gp, (char*)blob + g * 1024);
        }
        __syncthreads();

        short8 af[4], bfr[4];
#pragma unroll
        for (int i = 0; i < 4; i++)
            af[i] = *(const short8*)((char*)blob + ((wr * 4 + i) * 64 + lane) * 16);
#pragma unroll
        for (int j = 0; j < 4; j++)
            bfr[j] = *(const short8*)((char*)blob + 8192 + ((wc * 4 + j) * 64 + lane) * 16);
#pragma unroll
        for (int i = 0; i < 4; i++)
#pragma unroll
            for (int j = 0; j < 4; j++)
                acc[i][j] = __builtin_amdgcn_mfma_f32_16x16x32_bf16(af[i], bfr[j], acc[i][j], 0, 0, 0);
    }

    // epilogue: C/D layout col = l15, row = quad*4 + reg
#pragma unroll
    for (int i = 0; i < 4; i++) {
#pragma unroll
        for (int j = 0; j < 4; j++) {
            int colb = n0 + wc * 64 + j * 16 + l15;
            int rowb = m0 + wr * 64 + i * 16 + quad * 4;
            if (mode == 0) {
                float* Cf = (float*)C;
#pragma unroll
                for (int r = 0; r < 4; r++)
                    Cf[(size_t)(rowb + r) * DMODEL + colb] = acc[i][j][r];
            } else if (mode == 1) {
                unsigned short* Cb = (unsigned short*)C;
                int ip = (colb & 63) >> 1;
                bool odd = (colb & 1) != 0;
#pragma unroll
                for (int r = 0; r < 4; r++) {
                    int row = rowb + r;
                    int si = row & (S_LEN - 1);
                    float c = ct[si * 32 + ip];
                    float s = st[si * 32 + ip];
                    float v = acc[i][j][r];
                    float p = __shfl_xor(v, 1);
                    float rv = odd ? (p * s + v * c) : (v * c - p * s);
                    Cb[(size_t)row * DMODEL + colb] = f2b(rv);
                }
            } else {
                unsigned short* Cb = (unsigned short*)C;  // Vt [b*1024 + n][2048]
                int bb = rowb >> 11, srow = rowb & (S_LEN - 1);
                ushort4 pk;
                pk.x = f2b(acc[i][j][0]);
                pk.y = f2b(acc[i][j][1]);
                pk.z = f2b(acc[i][j][2]);
                pk.w = f2b(acc[i][j][3]);
                *(ushort4*)(Cb + (size_t)(bb * 1024 + colb) * S_LEN + srow) = pk;
            }
        }
    }
}

// ---------------------------------------------------------------------------
// MFMA flash attention (bf16 in, fp32 online softmax, bf16 out).
// grid (32 q-tiles, 32 b*h), 256 thr = 4 waves; wave owns 16 q-rows.
// K-tile = 32 keys: QK^T via 4 mfma (K frags direct from global, natural
// layout), softmax in C-layout (16-lane xor reduce), P -> LDS -> A-layout,
// PV via 4 mfma against Vt frags (direct from global). No __syncthreads.
// ---------------------------------------------------------------------------
__global__ __launch_bounds__(256) void attn_k(const unsigned short* __restrict__ Q,
                                              const unsigned short* __restrict__ K,
                                              const unsigned short* __restrict__ Vt,
                                              unsigned short* __restrict__ O) {
    __shared__ __align__(16) unsigned short Ps[4][16 * 40];  // per-wave, row stride 40
    const int tid = threadIdx.x;
    const int w = tid >> 6, lane = tid & 63;
    const int l15 = lane & 15, quad = lane >> 4;
    const int qt = blockIdx.x, bh = blockIdx.y;
    const int bb = bh >> 4, h = bh & 15;
    const int qbase = qt * 64 + w * 16;

    const size_t qoff = (size_t)(bb * S_LEN + qbase + l15) * DMODEL + h * DK;
    short8 aq0 = *(const short8*)(Q + qoff + quad * 8);
    short8 aq1 = *(const short8*)(Q + qoff + 32 + quad * 8);

    floatx4 o0 = {0.f, 0.f, 0.f, 0.f}, o1 = o0, o2 = o0, o3 = o0;
    float m[4], l[4];
#pragma unroll
    for (int r = 0; r < 4; r++) { m[r] = -1e30f; l[r] = 0.f; }

    const unsigned short* Kb = K + (size_t)(bb * S_LEN) * DMODEL + h * DK;
    const unsigned short* Vb = Vt + (size_t)(bb * 1024 + h * DK) * S_LEN;
    unsigned short* ps = &Ps[w][0];

    const int nkt = (qbase + 15) / 32 + 1;
    for (int kt = 0; kt < nkt; kt++) {
        const int kb = kt * 32;
        short8 kf00 = *(const short8*)(Kb + (size_t)(kb + l15) * DMODEL + quad * 8);
        short8 kf01 = *(const short8*)(Kb + (size_t)(kb + l15) * DMODEL + 32 + quad * 8);
        short8 kf10 = *(const short8*)(Kb + (size_t)(kb + 16 + l15) * DMODEL + quad * 8);
        short8 kf11 = *(const short8*)(Kb + (size_t)(kb + 16 + l15) * DMODEL + 32 + quad * 8);
        short8 vf0 = *(const short8*)(Vb + (size_t)(l15) * S_LEN + kb + quad * 8);
        short8 vf1 = *(const short8*)(Vb + (size_t)(16 + l15) * S_LEN + kb + quad * 8);
        short8 vf2 = *(const short8*)(Vb + (size_t)(32 + l15) * S_LEN + kb + quad * 8);
        short8 vf3 = *(const short8*)(Vb + (size_t)(48 + l15) * S_LEN + kb + quad * 8);

        floatx4 c0 = {0.f, 0.f, 0.f, 0.f}, c1 = c0;
        c0 = __builtin_amdgcn_mfma_f32_16x16x32_bf16(aq0, kf00, c0, 0, 0, 0);
        c0 = __builtin_amdgcn_mfma_f32_16x16x32_bf16(aq1, kf01, c0, 0, 0, 0);
        c1 = __builtin_amdgcn_mfma_f32_16x16x32_bf16(aq0, kf10, c1, 0, 0, 0);
        c1 = __builtin_amdgcn_mfma_f32_16x16x32_bf16(aq1, kf11, c1, 0, 0, 0);

        const int key0 = kb + l15, key1 = kb + 16 + l15;
        float alpha[4];
#pragma unroll
        for (int r = 0; r < 4; r++) {
            int row = qbase + quad * 4 + r;
            float s0 = (key0 <= row) ? c0[r] * 0.125f : -1e30f;
            float s1 = (key1 <= row) ? c1[r] * 0.125f : -1e30f;
            float mx = fmaxf(s0, s1);
#pragma unroll
            for (int d = 1; d < 16; d <<= 1) mx = fmaxf(mx, __shfl_xor(mx, d));
            float mnew = fmaxf(m[r], mx);
            alpha[r] = __expf(m[r] - mnew);
            float p0 = __expf(s0 - mnew);
            float p1 = __expf(s1 - mnew);
            float sum = p0 + p1;
#pragma unroll
            for (int d = 1; d < 16; d <<= 1) sum += __shfl_xor(sum, d);
            l[r] = l[r] * alpha[r] + sum;
            m[r] = mnew;
            ps[(quad * 4 + r) * 40 + l15] = f2b(p0);
            ps[(quad * 4 + r) * 40 + 16 + l15] = f2b(p1);
        }
#pragma unroll
        for (int r = 0; r < 4; r++) {
            o0[r] *= alpha[r]; o1[r] *= alpha[r];
            o2[r] *= alpha[r]; o3[r] *= alpha[r];
        }
        // P in A-layout: lane holds P[q = l15][key = quad*8 + j]
        short8 pf = *(const short8*)(ps + l15 * 40 + quad * 8);
        o0 = __builtin_amdgcn_mfma_f32_16x16x32_bf16(pf, vf0, o0, 0, 0, 0);
        o1 = __builtin_amdgcn_mfma_f32_16x16x32_bf16(pf, vf1, o1, 0, 0, 0);
        o2 = __builtin_amdgcn_mfma_f32_16x16x32_bf16(pf, vf2, o2, 0, 0, 0);
        o3 = __builtin_amdgcn_mfma_f32_16x16x32_bf16(pf, vf3, o3, 0, 0, 0);
    }

#pragma unroll
    for (int r = 0; r < 4; r++) {
        float inv = 1.0f / l[r];
        int row = qbase + quad * 4 + r;
        size_t base = (size_t)(bb * S_LEN + row) * DMODEL + h * DK;
        O[base + l15] = f2b(o0[r] * inv);
        O[base + 16 + l15] = f2b(o1[r] * inv);
        O[base + 32 + l15] = f2b(o2[r] * inv);
        O[base + 48 + l15] = f2b(o3[r] * inv);
    }
}

// ---------------------------------------------------------------------------
extern "C" void kernel_launch(void* const* d_in, const int* in_sizes, int n_in,
                              void* d_out, int out_size, void* d_ws,
                              size_t ws_size, hipStream_t stream) {
    const float* x = (const float*)d_in[0];
    const float* Wq = (const float*)d_in[1];
    const float* Wk = (const float*)d_in[2];
    const float* Wv = (const float*)d_in[3];
    const float* Wo = (const float*)d_in[4];
    const int* tokpos = (const int*)d_in[5];
    float* out = (float*)d_out;

    const size_t MD = (size_t)MTOT * DMODEL;  // 4194304
    const size_t WD = (size_t)DMODEL * DMODEL;
    unsigned short* xb = (unsigned short*)d_ws;
    unsigned short* Wqt = xb + MD;
    unsigned short* Wkt = Wqt + WD;
    unsigned short* Wvt = Wkt + WD;
    unsigned short* Wot = Wvt + WD;
    unsigned short* Q = Wot + WD;
    unsigned short* K = Q + MD;
    unsigned short* Vt = K + MD;   // [b*1024 + h*64 + d][s]
    unsigned short* O = Vt + MD;
    float* ct = (float*)(O + MD);
    float* st = ct + S_LEN * 32;

    rope_tables_k<<<dim3((S_LEN * 32) / 256), dim3(256), 0, stream>>>(tokpos, ct, st);
    cast_x_k<<<dim3(MD / 2048), dim3(256), 0, stream>>>(x, xb);
    trans_w_k<<<dim3(16, 16, 4), dim3(256), 0, stream>>>(Wq, Wk, Wv, Wo, Wqt, Wkt, Wvt, Wot);

    // Q,K (RoPE, bf16) and Vt (transposed bf16)
    mm_k<<<dim3(8, 32, 3), dim3(256), 0, stream>>>(xb, Wqt, Wkt, Wvt,
                                                   (void*)Q, (void*)K, (void*)Vt, ct, st, 0);
    attn_k<<<dim3(32, 32), dim3(256), 0, stream>>>(Q, K, Vt, O);
    // output projection, fp32 store
    mm_k<<<dim3(8, 32, 1), dim3(256), 0, stream>>>(O, Wot, Wot, Wot,
                                                   (void*)out, (void*)out, (void*)out, ct, st, 1);
}

// Round 3
// 314.753 us; speedup vs baseline: 4.9348x; 1.2727x over previous
//
#include <hip/hip_runtime.h>
#include <cmath>

#define S_LEN 2048
#define DMODEL 1024
#define NHEADS 16
#define DK 64
#define BATCH 2
#define MTOT (BATCH * S_LEN) /* 4096 */

using short8 = __attribute__((ext_vector_type(8))) short;
using floatx4 = __attribute__((ext_vector_type(4))) float;

// float -> bf16 bits, round-to-nearest-even
__device__ __forceinline__ unsigned short f2b(float f) {
    union { float f; unsigned u; } v; v.f = f;
    unsigned r = v.u + 0x7fff + ((v.u >> 16) & 1);
    return (unsigned short)(r >> 16);
}

// async global->LDS, 16 bytes per lane. LDS dest: wave-uniform base + lane*16.
__device__ __forceinline__ void gload16(const void* g, void* l) {
    __builtin_amdgcn_global_load_lds(
        (const __attribute__((address_space(1))) unsigned int*)g,
        (__attribute__((address_space(3))) unsigned int*)l, 16, 0, 0);
}

// ---------------------------------------------------------------------------
// RoPE tables: ct/st[si*32 + ip] = cos/sin(pos[si] * 10000^(-2ip/64))
// ---------------------------------------------------------------------------
__global__ void rope_tables_k(const int* __restrict__ tokpos,
                              float* __restrict__ ct, float* __restrict__ st) {
    int idx = blockIdx.x * blockDim.x + threadIdx.x;
    int si = idx >> 5;
    int ip = idx & 31;
    float pos = (float)tokpos[si];
    float inv_freq = powf(10000.0f, -(float)(2 * ip) / 64.0f);
    float ang = pos * inv_freq;
    ct[idx] = cosf(ang);
    st[idx] = sinf(ang);
}

// ---------------------------------------------------------------------------
// x (fp32) -> xb (bf16), 8 elements/thread
// ---------------------------------------------------------------------------
__global__ __launch_bounds__(256) void cast_x_k(const float* __restrict__ x,
                                                unsigned short* __restrict__ xb) {
    int i = (blockIdx.x * 256 + threadIdx.x) * 8;
    float4 a = *(const float4*)(x + i);
    float4 b = *(const float4*)(x + i + 4);
    short8 o;
    o[0] = f2b(a.x); o[1] = f2b(a.y); o[2] = f2b(a.z); o[3] = f2b(a.w);
    o[4] = f2b(b.x); o[5] = f2b(b.y); o[6] = f2b(b.z); o[7] = f2b(b.w);
    *(short8*)(xb + i) = o;
}

// ---------------------------------------------------------------------------
// W[k][n] fp32 -> Wt[n][k] bf16 (64x64 LDS tile transpose), z selects matrix
// ---------------------------------------------------------------------------
__global__ __launch_bounds__(256) void trans_w_k(
    const float* W0, const float* W1, const float* W2, const float* W3,
    unsigned short* T0, unsigned short* T1, unsigned short* T2, unsigned short* T3) {
    __shared__ float t[64][65];
    int z = blockIdx.z;
    const float* W = z == 0 ? W0 : z == 1 ? W1 : z == 2 ? W2 : W3;
    unsigned short* T = z == 0 ? T0 : z == 1 ? T1 : z == 2 ? T2 : T3;
    int n0 = blockIdx.x * 64, k0 = blockIdx.y * 64;
    int rr = threadIdx.x >> 6, cc = threadIdx.x & 63;
#pragma unroll
    for (int r = 0; r < 16; r++) {
        int row = r * 4 + rr;
        t[row][cc] = W[(size_t)(k0 + row) * DMODEL + n0 + cc];
    }
    __syncthreads();
#pragma unroll
    for (int r = 0; r < 16; r++) {
        int row = r * 4 + rr;
        T[(size_t)(n0 + row) * DMODEL + k0 + cc] = f2b(t[cc][row]);
    }
}

// ---------------------------------------------------------------------------
// bf16 MFMA GEMM: C[4096,1024] = A[4096,1024] x Bt^T  (Bt is [N][K] bf16)
// 128x128 tile, BK=32, 256 thr = 4 waves, each wave 64x64 = 4x4 mfma 16x16x32.
// kind 0: z<2 -> RoPE+bf16 store; z==2 -> transposed bf16 store (Vt).
// kind 1: plain fp32 store.
// ---------------------------------------------------------------------------
__global__ __launch_bounds__(256) void mm_k(
    const unsigned short* __restrict__ A,
    const unsigned short* __restrict__ Bt0, const unsigned short* __restrict__ Bt1,
    const unsigned short* __restrict__ Bt2,
    void* C0, void* C1, void* C2,
    const float* __restrict__ ct, const float* __restrict__ st, int kind) {
    __shared__ __align__(16) unsigned short blob[8192];  // 16 KB: A 8K + B 8K bytes

    const int z = blockIdx.z;
    const unsigned short* Bt = z == 0 ? Bt0 : z == 1 ? Bt1 : Bt2;
    void* C = z == 0 ? C0 : z == 1 ? C1 : C2;
    const int mode = (kind == 1) ? 0 : (z == 2 ? 2 : 1);

    const int tid = threadIdx.x;
    const int w = tid >> 6, lane = tid & 63;
    const int l15 = lane & 15, quad = lane >> 4;
    const int wr = w >> 1, wc = w & 1;
    const int m0 = blockIdx.y * 128, n0 = blockIdx.x * 128;

    floatx4 acc[4][4];
#pragma unroll
    for (int i = 0; i < 4; i++)
#pragma unroll
        for (int j = 0; j < 4; j++) acc[i][j] = (floatx4){0.f, 0.f, 0.f, 0.f};

    for (int k0 = 0; k0 < DMODEL; k0 += 32) {
        if (k0) __syncthreads();
#pragma unroll
        for (int it = 0; it < 4; it++) {
            int g = it * 4 + w;  // wave-uniform group 0..15 (A: 0..7, B: 8..15)
            const unsigned short* gp;
            if (g < 8)
                gp = A + (size_t)(m0 + g * 16 + l15) * DMODEL + k0 + (lane >> 4) * 8;
            else
                gp = Bt + (size_t)(n0 + (g - 8) * 16 + l15) * DMODEL + k0 + (lane >> 4) * 8;
            gload16(gp, (char*)blob + g * 1024);
        }
        __syncthreads();

        short8 af[4], bfr[4];
#pragma unroll
        for (int i = 0; i < 4; i++)
            af[i] = *(const short8*)((char*)blob + ((wr * 4 + i) * 64 + lane) * 16);
#pragma unroll
        for (int j = 0; j < 4; j++)
            bfr[j] = *(const short8*)((char*)blob + 8192 + ((wc * 4 + j) * 64 + lane) * 16);
#pragma unroll
        for (int i = 0; i < 4; i++)
#pragma unroll
            for (int j = 0; j < 4; j++)
                acc[i][j] = __builtin_amdgcn_mfma_f32_16x16x32_bf16(af[i], bfr[j], acc[i][j], 0, 0, 0);
    }

    // epilogue: C/D layout col = l15, row = quad*4 + reg
#pragma unroll
    for (int i = 0; i < 4; i++) {
#pragma unroll
        for (int j = 0; j < 4; j++) {
            int colb = n0 + wc * 64 + j * 16 + l15;
            int rowb = m0 + wr * 64 + i * 16 + quad * 4;
            if (mode == 0) {
                float* Cf = (float*)C;
#pragma unroll
                for (int r = 0; r < 4; r++)
                    Cf[(size_t)(rowb + r) * DMODEL + colb] = acc[i][j][r];
            } else if (mode == 1) {
                unsigned short* Cb = (unsigned short*)C;
                int ip = (colb & 63) >> 1;
                bool odd = (colb & 1) != 0;
#pragma unroll
                for (int r = 0; r < 4; r++) {
                    int row = rowb + r;
                    int si = row & (S_LEN - 1);
                    float c = ct[si * 32 + ip];
                    float s = st[si * 32 + ip];
                    float v = acc[i][j][r];
                    float p = __shfl_xor(v, 1);
                    float rv = odd ? (p * s + v * c) : (v * c - p * s);
                    Cb[(size_t)row * DMODEL + colb] = f2b(rv);
                }
            } else {
                unsigned short* Cb = (unsigned short*)C;  // Vt [b*1024 + n][2048]
                int bb = rowb >> 11, srow = rowb & (S_LEN - 1);
                ushort4 pk;
                pk.x = f2b(acc[i][j][0]);
                pk.y = f2b(acc[i][j][1]);
                pk.z = f2b(acc[i][j][2]);
                pk.w = f2b(acc[i][j][3]);
                *(ushort4*)(Cb + (size_t)(bb * 1024 + colb) * S_LEN + srow) = pk;
            }
        }
    }
}

// ---------------------------------------------------------------------------
// MFMA flash attention, transposed-score form.
// S^T = K·Q^T  (C layout: col=query, row=key)  -> per-lane online softmax
// (one query per lane, 2 shuffle stages across quads) -> P via LDS ->
// O^T = V^T·P^T. Double-buffered K/V register prefetch. 1D grid, longest
// q-tiles launched first for load balance.
// ---------------------------------------------------------------------------
__global__ __launch_bounds__(256, 4) void attn_k(const unsigned short* __restrict__ Q,
                                                 const unsigned short* __restrict__ K,
                                                 const unsigned short* __restrict__ Vt,
                                                 unsigned short* __restrict__ O) {
    __shared__ __align__(16) unsigned short Ps[4][16 * 40];  // per-wave P, row stride 40
    __shared__ __align__(16) unsigned short Os[4][16 * 72];  // per-wave O transpose bounce
    const int tid = threadIdx.x;
    const int w = tid >> 6, lane = tid & 63;
    const int l15 = lane & 15, quad = lane >> 4;
    const int idx = blockIdx.x;
    const int qt = 31 - (idx >> 5);  // longest blocks dispatch first
    const int bh = idx & 31;
    const int bb = bh >> 4, h = bh & 15;
    const int qbase = qt * 64 + w * 16;
    const int qrow = qbase + l15;  // this lane's query row

    // Q fragment, B-operand layout: lane=col(query), quad*8=k dims
    const size_t qoff = (size_t)(bb * S_LEN + qbase + l15) * DMODEL + h * DK;
    short8 aq0 = *(const short8*)(Q + qoff + quad * 8);
    short8 aq1 = *(const short8*)(Q + qoff + 32 + quad * 8);

    floatx4 o[4];
#pragma unroll
    for (int f = 0; f < 4; f++) o[f] = (floatx4){0.f, 0.f, 0.f, 0.f};
    float mv = -1e30f, lv = 0.f;

    const unsigned short* Kb = K + (size_t)(bb * S_LEN) * DMODEL + h * DK;
    const unsigned short* Vb = Vt + (size_t)(bb * 1024 + h * DK) * S_LEN;
    unsigned short* ps = &Ps[w][0];

    short8 kA[4], vA[4], kB[4], vB[4];

    auto ldKV = [&](short8* kf, short8* vf, int kb) {
        const unsigned short* kp = Kb + (size_t)(kb + l15) * DMODEL + quad * 8;
        kf[0] = *(const short8*)(kp);
        kf[1] = *(const short8*)(kp + 32);
        kf[2] = *(const short8*)(kp + (size_t)16 * DMODEL);
        kf[3] = *(const short8*)(kp + (size_t)16 * DMODEL + 32);
        const unsigned short* vp = Vb + (size_t)l15 * S_LEN + kb + quad * 8;
        vf[0] = *(const short8*)(vp);
        vf[1] = *(const short8*)(vp + (size_t)16 * S_LEN);
        vf[2] = *(const short8*)(vp + (size_t)32 * S_LEN);
        vf[3] = *(const short8*)(vp + (size_t)48 * S_LEN);
    };

    auto step = [&](const short8* kf, const short8* vf, int kb) {
        floatx4 c0 = {0.f, 0.f, 0.f, 0.f}, c1 = c0;
        c0 = __builtin_amdgcn_mfma_f32_16x16x32_bf16(kf[0], aq0, c0, 0, 0, 0);
        c0 = __builtin_amdgcn_mfma_f32_16x16x32_bf16(kf[1], aq1, c0, 0, 0, 0);
        c1 = __builtin_amdgcn_mfma_f32_16x16x32_bf16(kf[2], aq0, c1, 0, 0, 0);
        c1 = __builtin_amdgcn_mfma_f32_16x16x32_bf16(kf[3], aq1, c1, 0, 0, 0);

        float s[8];
#pragma unroll
        for (int r = 0; r < 4; r++) {
            int key0 = kb + quad * 4 + r;
            s[r] = (key0 <= qrow) ? c0[r] * 0.125f : -1e30f;
            s[4 + r] = (key0 + 16 <= qrow) ? c1[r] * 0.125f : -1e30f;
        }
        float mx = fmaxf(fmaxf(fmaxf(s[0], s[1]), fmaxf(s[2], s[3])),
                         fmaxf(fmaxf(s[4], s[5]), fmaxf(s[6], s[7])));
        mx = fmaxf(mx, __shfl_xor(mx, 16));
        mx = fmaxf(mx, __shfl_xor(mx, 32));
        float mnew = fmaxf(mv, mx);
        float alpha = __expf(mv - mnew);
        float p[8], sum = 0.f;
#pragma unroll
        for (int i = 0; i < 8; i++) {
            p[i] = __expf(s[i] - mnew);
            sum += p[i];
        }
        sum += __shfl_xor(sum, 16);
        sum += __shfl_xor(sum, 32);
        lv = lv * alpha + sum;
        mv = mnew;

        ushort4 pk0, pk1;
        pk0.x = f2b(p[0]); pk0.y = f2b(p[1]); pk0.z = f2b(p[2]); pk0.w = f2b(p[3]);
        pk1.x = f2b(p[4]); pk1.y = f2b(p[5]); pk1.z = f2b(p[6]); pk1.w = f2b(p[7]);
        *(ushort4*)(ps + l15 * 40 + quad * 4) = pk0;       // P[q=l15][key=quad*4+r]
        *(ushort4*)(ps + l15 * 40 + 16 + quad * 4) = pk1;  // keys 16..31

#pragma unroll
        for (int f = 0; f < 4; f++) {
            o[f][0] *= alpha; o[f][1] *= alpha;
            o[f][2] *= alpha; o[f][3] *= alpha;
        }
        // B-operand frag of P^T: lane=col(query)=l15, keys quad*8..+7
        short8 pf = *(const short8*)(ps + l15 * 40 + quad * 8);
#pragma unroll
        for (int f = 0; f < 4; f++)
            o[f] = __builtin_amdgcn_mfma_f32_16x16x32_bf16(vf[f], pf, o[f], 0, 0, 0);
    };

    const int nkt = (qbase + 15) / 32 + 1;
    ldKV(kA, vA, 0);
    int kt = 0;
    while (true) {
        if (kt + 1 < nkt) ldKV(kB, vB, (kt + 1) * 32);
        step(kA, vA, kt * 32);
        kt++;
        if (kt >= nkt) break;
        if (kt + 1 < nkt) ldKV(kA, vA, (kt + 1) * 32);
        step(kB, vB, kt * 32);
        kt++;
        if (kt >= nkt) break;
    }

    // epilogue: un-transpose O^T via LDS, coalesced 16B stores
    float inv = 1.0f / lv;
    unsigned short* os = &Os[w][0];
#pragma unroll
    for (int f = 0; f < 4; f++) {
        ushort4 pk;
        pk.x = f2b(o[f][0] * inv);
        pk.y = f2b(o[f][1] * inv);
        pk.z = f2b(o[f][2] * inv);
        pk.w = f2b(o[f][3] * inv);
        *(ushort4*)(os + l15 * 72 + f * 16 + quad * 4) = pk;  // row=q(l15), d=f*16+quad*4
    }
    short8 r0 = *(const short8*)(os + l15 * 72 + quad * 8);
    short8 r1 = *(const short8*)(os + l15 * 72 + 32 + quad * 8);
    size_t obase = (size_t)(bb * S_LEN + qbase + l15) * DMODEL + h * DK;
    *(short8*)(O + obase + quad * 8) = r0;
    *(short8*)(O + obase + 32 + quad * 8) = r1;
}

// ---------------------------------------------------------------------------
extern "C" void kernel_launch(void* const* d_in, const int* in_sizes, int n_in,
                              void* d_out, int out_size, void* d_ws,
                              size_t ws_size, hipStream_t stream) {
    const float* x = (const float*)d_in[0];
    const float* Wq = (const float*)d_in[1];
    const float* Wk = (const float*)d_in[2];
    const float* Wv = (const float*)d_in[3];
    const float* Wo = (const float*)d_in[4];
    const int* tokpos = (const int*)d_in[5];
    float* out = (float*)d_out;

    const size_t MD = (size_t)MTOT * DMODEL;  // 4194304
    const size_t WD = (size_t)DMODEL * DMODEL;
    unsigned short* xb = (unsigned short*)d_ws;
    unsigned short* Wqt = xb + MD;
    unsigned short* Wkt = Wqt + WD;
    unsigned short* Wvt = Wkt + WD;
    unsigned short* Wot = Wvt + WD;
    unsigned short* Q = Wot + WD;
    unsigned short* K = Q + MD;
    unsigned short* Vt = K + MD;  // [b*1024 + h*64 + d][s]
    unsigned short* O = Vt + MD;
    float* ct = (float*)(O + MD);
    float* st = ct + S_LEN * 32;

    rope_tables_k<<<dim3((S_LEN * 32) / 256), dim3(256), 0, stream>>>(tokpos, ct, st);
    cast_x_k<<<dim3(MD / 2048), dim3(256), 0, stream>>>(x, xb);
    trans_w_k<<<dim3(16, 16, 4), dim3(256), 0, stream>>>(Wq, Wk, Wv, Wo, Wqt, Wkt, Wvt, Wot);

    // Q,K (RoPE, bf16) and Vt (transposed bf16)
    mm_k<<<dim3(8, 32, 3), dim3(256), 0, stream>>>(xb, Wqt, Wkt, Wvt,
                                                   (void*)Q, (void*)K, (void*)Vt, ct, st, 0);
    attn_k<<<dim3(1024), dim3(256), 0, stream>>>(Q, K, Vt, O);
    // output projection, fp32 store
    mm_k<<<dim3(8, 32, 1), dim3(256), 0, stream>>>(O, Wot, Wot, Wot,
                                                   (void*)out, (void*)out, (void*)out, ct, st, 1);
}

// Round 5
// 223.970 us; speedup vs baseline: 6.9350x; 1.4053x over previous
//
#include <hip/hip_runtime.h>
#include <cmath>

#define S_LEN 2048
#define DMODEL 1024
#define NHEADS 16
#define DK 64
#define BATCH 2
#define MTOT (BATCH * S_LEN) /* 4096 */

using short8 = __attribute__((ext_vector_type(8))) short;
using floatx4 = __attribute__((ext_vector_type(4))) float;

// float -> bf16 bits, round-to-nearest-even
__device__ __forceinline__ unsigned short f2b(float f) {
    union { float f; unsigned u; } v; v.f = f;
    unsigned r = v.u + 0x7fff + ((v.u >> 16) & 1);
    return (unsigned short)(r >> 16);
}

// async global->LDS, 16 B/lane. LDS dest is wave-uniform base (+lane*16 by HW).
__device__ __forceinline__ void gload16(const void* g, void* l) {
    __builtin_amdgcn_global_load_lds(
        (const __attribute__((address_space(1))) unsigned int*)g,
        (__attribute__((address_space(3))) unsigned int*)l, 16, 0, 0);
}

// ---------------------------------------------------------------------------
// RoPE tables: ct/st[si*32 + ip] = cos/sin(pos[si] * 10000^(-2ip/64))
// ---------------------------------------------------------------------------
__global__ void rope_tables_k(const int* __restrict__ tokpos,
                              float* __restrict__ ct, float* __restrict__ st) {
    int idx = blockIdx.x * blockDim.x + threadIdx.x;
    int si = idx >> 5;
    int ip = idx & 31;
    float pos = (float)tokpos[si];
    float inv_freq = powf(10000.0f, -(float)(2 * ip) / 64.0f);
    float ang = pos * inv_freq;
    ct[idx] = cosf(ang);
    st[idx] = sinf(ang);
}

// ---------------------------------------------------------------------------
// x (fp32) -> xb (bf16), 8 elements/thread
// ---------------------------------------------------------------------------
__global__ __launch_bounds__(256) void cast_x_k(const float* __restrict__ x,
                                                unsigned short* __restrict__ xb) {
    int i = (blockIdx.x * 256 + threadIdx.x) * 8;
    float4 a = *(const float4*)(x + i);
    float4 b = *(const float4*)(x + i + 4);
    short8 o;
    o[0] = f2b(a.x); o[1] = f2b(a.y); o[2] = f2b(a.z); o[3] = f2b(a.w);
    o[4] = f2b(b.x); o[5] = f2b(b.y); o[6] = f2b(b.z); o[7] = f2b(b.w);
    *(short8*)(xb + i) = o;
}

// ---------------------------------------------------------------------------
// W[k][n] fp32 -> Wt[n][k] bf16 (64x64 LDS tile transpose), z selects matrix.
// z<2 (Wq,Wk): head-dim columns PERMUTED — within each 64-col head, original
// col d goes to position (d even ? d/2 : 32 + d/2). This makes the GEMM
// output col c<32 = x_even of pair c, col c+32 = x_odd of pair c, so the
// RoPE epilogue needs no cross-lane exchange. QK^T is invariant under the
// shared permutation of Q and K. n0 is 64-aligned => head-aligned tiles;
// the permuted row is wave-uniform so store coalescing is unchanged.
// ---------------------------------------------------------------------------
__global__ __launch_bounds__(256) void trans_w_k(
    const float* W0, const float* W1, const float* W2, const float* W3,
    unsigned short* T0, unsigned short* T1, unsigned short* T2, unsigned short* T3) {
    __shared__ float t[64][65];
    int z = blockIdx.z;
    const float* W = z == 0 ? W0 : z == 1 ? W1 : z == 2 ? W2 : W3;
    unsigned short* T = z == 0 ? T0 : z == 1 ? T1 : z == 2 ? T2 : T3;
    const bool perm = (z < 2);
    int n0 = blockIdx.x * 64, k0 = blockIdx.y * 64;
    int rr = threadIdx.x >> 6, cc = threadIdx.x & 63;
#pragma unroll
    for (int r = 0; r < 16; r++) {
        int row = r * 4 + rr;
        t[row][cc] = W[(size_t)(k0 + row) * DMODEL + n0 + cc];
    }
    __syncthreads();
#pragma unroll
    for (int r = 0; r < 16; r++) {
        int row = r * 4 + rr;  // original col within head
        int drow = perm ? (((row & 1) ? 32 : 0) + (row >> 1)) : row;
        T[(size_t)(n0 + drow) * DMODEL + k0 + cc] = f2b(t[cc][row]);
    }
}

// ---------------------------------------------------------------------------
// V[s][d] bf16 -> Vt[b*1024 + d][s] bf16, 64x64 LDS tiles
// ---------------------------------------------------------------------------
__global__ __launch_bounds__(256) void vtrans_k(const unsigned short* __restrict__ V,
                                                unsigned short* __restrict__ Vt) {
    __shared__ unsigned short t[64][72];  // 144 B rows: 16B-aligned, bank-spread
    const int tid = threadIdx.x;
    const int s0 = blockIdx.x * 64, d0 = blockIdx.y * 64;
    const int bb = s0 >> 11;
#pragma unroll
    for (int it = 0; it < 4; it++) {
        int e = (it * 256 + tid) * 4;  // flat ushort4 id: row=s, col=d
        int r = e >> 6, c = e & 63;
        *(ushort4*)&t[r][c] = *(const ushort4*)(V + (size_t)(s0 + r) * DMODEL + d0 + c);
    }
    __syncthreads();
#pragma unroll
    for (int it = 0; it < 4; it++) {
        int e = (it * 256 + tid) * 4;  // flat ushort4 id: row=d, col=s
        int r = e >> 6, c = e & 63;
        ushort4 v;
        v.x = t[c + 0][r]; v.y = t[c + 1][r];
        v.z = t[c + 2][r]; v.w = t[c + 3][r];
        *(ushort4*)(Vt + (size_t)(bb * 1024 + d0 + r) * S_LEN + (s0 & (S_LEN - 1)) + c) = v;
    }
}

// ---------------------------------------------------------------------------
// bf16 MFMA GEMM: C[4096,1024] = A[4096,1024] x Bt^T  (Bt is [N][K] bf16)
// 128x128 tile, BK=32, 4 waves, 4x4 mfma 16x16x32 per wave.
// kind 0: z<2 -> RoPE (permuted-d weights, shuffle-free) bf16; z==2 -> plain
// bf16 (V). kind 1: plain fp32 store (final output).
// ---------------------------------------------------------------------------
__global__ __launch_bounds__(256) void mm_k(
    const unsigned short* __restrict__ A,
    const unsigned short* __restrict__ Bt0, const unsigned short* __restrict__ Bt1,
    const unsigned short* __restrict__ Bt2,
    void* C0, void* C1, void* C2,
    const float* __restrict__ ct, const float* __restrict__ st, int kind) {
    __shared__ __align__(16) unsigned short blob[8192];  // 16 KB: A 8K + B 8K bytes

    const int z = blockIdx.z;
    const unsigned short* Bt = z == 0 ? Bt0 : z == 1 ? Bt1 : Bt2;
    void* C = z == 0 ? C0 : z == 1 ? C1 : C2;
    const int mode = (kind == 1) ? 0 : (z == 2 ? 3 : 1);

    const int tid = threadIdx.x;
    const int w = tid >> 6, lane = tid & 63;
    const int l15 = lane & 15, quad = lane >> 4;
    const int wr = w >> 1, wc = w & 1;
    const int m0 = blockIdx.y * 128, n0 = blockIdx.x * 128;

    floatx4 acc[4][4];
#pragma unroll
    for (int i = 0; i < 4; i++)
#pragma unroll
        for (int j = 0; j < 4; j++) acc[i][j] = (floatx4){0.f, 0.f, 0.f, 0.f};

    for (int k0 = 0; k0 < DMODEL; k0 += 32) {
        if (k0) __syncthreads();
#pragma unroll
        for (int it = 0; it < 4; it++) {
            int g = it * 4 + w;  // wave-uniform group 0..15 (A: 0..7, B: 8..15)
            const unsigned short* gp;
            if (g < 8)
                gp = A + (size_t)(m0 + g * 16 + l15) * DMODEL + k0 + (lane >> 4) * 8;
            else
                gp = Bt + (size_t)(n0 + (g - 8) * 16 + l15) * DMODEL + k0 + (lane >> 4) * 8;
            gload16(gp, (char*)blob + g * 1024);
        }
        __syncthreads();

        short8 af[4], bfr[4];
#pragma unroll
        for (int i = 0; i < 4; i++)
            af[i] = *(const short8*)((char*)blob + ((wr * 4 + i) * 64 + lane) * 16);
#pragma unroll
        for (int j = 0; j < 4; j++)
            bfr[j] = *(const short8*)((char*)blob + 8192 + ((wc * 4 + j) * 64 + lane) * 16);
#pragma unroll
        for (int i = 0; i < 4; i++)
#pragma unroll
            for (int j = 0; j < 4; j++)
                acc[i][j] = __builtin_amdgcn_mfma_f32_16x16x32_bf16(af[i], bfr[j], acc[i][j], 0, 0, 0);
    }

    // epilogue: C/D layout col = l15, row = quad*4 + reg
#pragma unroll
    for (int i = 0; i < 4; i++) {
        const int rowb = m0 + wr * 64 + i * 16 + quad * 4;
        if (mode == 0) {
            float* Cf = (float*)C;
#pragma unroll
            for (int j = 0; j < 4; j++) {
                int colb = n0 + wc * 64 + j * 16 + l15;
#pragma unroll
                for (int r = 0; r < 4; r++)
                    Cf[(size_t)(rowb + r) * DMODEL + colb] = acc[i][j][r];
            }
        } else if (mode == 1) {
            unsigned short* Cb = (unsigned short*)C;
#pragma unroll
            for (int jh = 0; jh < 2; jh++) {
                int ip = jh * 16 + l15;                   // pair index within head
                int cole = n0 + wc * 64 + jh * 16 + l15;  // even-member column (d'<32)
#pragma unroll
                for (int r = 0; r < 4; r++) {
                    int row = rowb + r;
                    int si = row & (S_LEN - 1);
                    float c = ct[si * 32 + ip];
                    float s = st[si * 32 + ip];
                    float e = acc[i][jh][r];       // x_even (permuted weights)
                    float od = acc[i][jh + 2][r];  // x_odd (partner col, same thread)
                    Cb[(size_t)row * DMODEL + cole] = f2b(e * c - od * s);
                    Cb[(size_t)row * DMODEL + cole + 32] = f2b(e * s + od * c);
                }
            }
        } else {
            unsigned short* Cb = (unsigned short*)C;
#pragma unroll
            for (int j = 0; j < 4; j++) {
                int colb = n0 + wc * 64 + j * 16 + l15;
#pragma unroll
                for (int r = 0; r < 4; r++)
                    Cb[(size_t)(rowb + r) * DMODEL + colb] = f2b(acc[i][j][r]);
            }
        }
    }
}

// ---------------------------------------------------------------------------
// Block-cooperative MFMA flash attention, 64-key tiles.
// Grid 1024 = (32 q-tiles x 32 bh), longest q-tiles first; 4 waves/block,
// wave owns 16 queries. K/V staged per-block into double-buffered LDS
// fragment blobs via global_load_lds (1 barrier/iter, nkt = qt+1 uniform).
// S^T = K Q^T (C: col=query, row=key) -> per-lane softmax, max-reduce 2 shfl,
// l-sum deferred to end. P via per-wave LDS -> O^T = V^T P^T.
// ---------------------------------------------------------------------------
__global__ __launch_bounds__(256) void attn_k(const unsigned short* __restrict__ Q,
                                              const unsigned short* __restrict__ K,
                                              const unsigned short* __restrict__ Vt,
                                              unsigned short* __restrict__ O) {
    __shared__ __align__(16) unsigned short Kblob[2][4096];  // 8 KB/buf: 8 grp x 512
    __shared__ __align__(16) unsigned short Vblob[2][4096];
    __shared__ __align__(16) unsigned short Ps[4][16 * 72];  // per-wave P / O-bounce

    const int tid = threadIdx.x;
    const int w = tid >> 6, lane = tid & 63;
    const int l15 = lane & 15, quad = lane >> 4;
    const int idx = blockIdx.x;
    const int qt = 31 - (idx >> 5);  // longest blocks dispatch first
    const int bh = idx & 31;
    const int bb = bh >> 4, h = bh & 15;
    const int qbase = qt * 64 + w * 16;
    const int qrow = qbase + l15;

    // Q fragment (B-operand: col=query=l15, k=quad*8), d-halves 0/1
    const size_t qoff = (size_t)(bb * S_LEN + qbase + l15) * DMODEL + h * DK;
    short8 aq0 = *(const short8*)(Q + qoff + quad * 8);
    short8 aq1 = *(const short8*)(Q + qoff + 32 + quad * 8);

    floatx4 o[4];
#pragma unroll
    for (int f = 0; f < 4; f++) o[f] = (floatx4){0.f, 0.f, 0.f, 0.f};
    float mv = -1e30f, lv = 0.f;

    const unsigned short* Kb = K + (size_t)(bb * S_LEN) * DMODEL + h * DK;
    const unsigned short* Vb = Vt + (size_t)(bb * 1024 + h * DK) * S_LEN;
    unsigned short* ps = &Ps[w][0];

    // stage 64-key K/V tile into blob buffer b (4 gload16/thread)
    auto stage = [&](int b, int kb) {
#pragma unroll
        for (int it = 0; it < 4; it++) {
            int g = it * 4 + w;  // wave-uniform 0..15; 0..7 K-groups, 8..15 V-groups
            if (g < 8) {
                const unsigned short* gp =
                    Kb + (size_t)(kb + (g >> 1) * 16 + l15) * DMODEL + (g & 1) * 32 + quad * 8;
                gload16(gp, (char*)&Kblob[b][0] + g * 1024);
            } else {
                int gv = g - 8;
                const unsigned short* gp =
                    Vb + (size_t)((gv >> 1) * 16 + l15) * S_LEN + kb + (gv & 1) * 32 + quad * 8;
                gload16(gp, (char*)&Vblob[b][0] + gv * 1024);
            }
        }
    };

    const int nkt = qt + 1;  // uniform across waves
    stage(0, 0);
    for (int kt = 0; kt < nkt; kt++) {
        const int b = kt & 1;
        const int kb = kt * 64;
        __syncthreads();  // staging of buf b complete; buf b^1 reads done
        if (kt + 1 < nkt) stage(b ^ 1, (kt + 1) * 64);

        // QK^T: S^T[key 64][q 16]
        const unsigned short* kbb = &Kblob[b][0];
        floatx4 c[4];
#pragma unroll
        for (int g = 0; g < 4; g++) {
            short8 kf0 = *(const short8*)(kbb + (g * 2 + 0) * 512 + lane * 8);
            short8 kf1 = *(const short8*)(kbb + (g * 2 + 1) * 512 + lane * 8);
            floatx4 t = {0.f, 0.f, 0.f, 0.f};
            t = __builtin_amdgcn_mfma_f32_16x16x32_bf16(kf0, aq0, t, 0, 0, 0);
            c[g] = __builtin_amdgcn_mfma_f32_16x16x32_bf16(kf1, aq1, t, 0, 0, 0);
        }

        // softmax over 16 keys/lane (keys kb + g*16 + quad*4 + r)
        float sv[16];
#pragma unroll
        for (int g = 0; g < 4; g++)
#pragma unroll
            for (int r = 0; r < 4; r++) {
                int key = kb + g * 16 + quad * 4 + r;
                sv[g * 4 + r] = (key <= qrow) ? c[g][r] * 0.125f : -1e30f;
            }
        float mx = sv[0];
#pragma unroll
        for (int i = 1; i < 16; i++) mx = fmaxf(mx, sv[i]);
        mx = fmaxf(mx, __shfl_xor(mx, 16));
        mx = fmaxf(mx, __shfl_xor(mx, 32));
        float mnew = fmaxf(mv, mx);
        float alpha = __expf(mv - mnew);
        mv = mnew;
        float p[16], psum = 0.f;
#pragma unroll
        for (int i = 0; i < 16; i++) {
            p[i] = __expf(sv[i] - mnew);
            psum += p[i];
        }
        lv = lv * alpha + psum;  // per-lane partial; cross-quad reduce at end

        // P -> LDS (row=q l15, key = g*16+quad*4..+3), stride 72 shorts
#pragma unroll
        for (int g = 0; g < 4; g++) {
            ushort4 pk;
            pk.x = f2b(p[g * 4 + 0]); pk.y = f2b(p[g * 4 + 1]);
            pk.z = f2b(p[g * 4 + 2]); pk.w = f2b(p[g * 4 + 3]);
            *(ushort4*)(ps + l15 * 72 + g * 16 + quad * 4) = pk;
        }
#pragma unroll
        for (int f = 0; f < 4; f++) {
            o[f][0] *= alpha; o[f][1] *= alpha;
            o[f][2] *= alpha; o[f][3] *= alpha;
        }
        // P^T B-frags (col=q l15, keys quad*8 / +32)
        short8 pf0 = *(const short8*)(ps + l15 * 72 + quad * 8);
        short8 pf1 = *(const short8*)(ps + l15 * 72 + 32 + quad * 8);
        const unsigned short* vbb = &Vblob[b][0];
#pragma unroll
        for (int f = 0; f < 4; f++) {
            short8 vf0 = *(const short8*)(vbb + (f * 2 + 0) * 512 + lane * 8);
            short8 vf1 = *(const short8*)(vbb + (f * 2 + 1) * 512 + lane * 8);
            o[f] = __builtin_amdgcn_mfma_f32_16x16x32_bf16(vf0, pf0, o[f], 0, 0, 0);
            o[f] = __builtin_amdgcn_mfma_f32_16x16x32_bf16(vf1, pf1, o[f], 0, 0, 0);
        }
    }

    // final l reduction across quads, then un-transpose O^T via LDS
    lv += __shfl_xor(lv, 16);
    lv += __shfl_xor(lv, 32);
    float inv = 1.0f / lv;
    __syncthreads();  // safe reuse of Ps region
#pragma unroll
    for (int f = 0; f < 4; f++) {
        ushort4 pk;
        pk.x = f2b(o[f][0] * inv);
        pk.y = f2b(o[f][1] * inv);
        pk.z = f2b(o[f][2] * inv);
        pk.w = f2b(o[f][3] * inv);
        *(ushort4*)(ps + l15 * 72 + f * 16 + quad * 4) = pk;  // row=q, d=f*16+quad*4
    }
    short8 r0 = *(const short8*)(ps + l15 * 72 + quad * 8);
    short8 r1 = *(const short8*)(ps + l15 * 72 + 32 + quad * 8);
    size_t obase = (size_t)(bb * S_LEN + qbase + l15) * DMODEL + h * DK;
    *(short8*)(O + obase + quad * 8) = r0;
    *(short8*)(O + obase + 32 + quad * 8) = r1;
}

// ---------------------------------------------------------------------------
extern "C" void kernel_launch(void* const* d_in, const int* in_sizes, int n_in,
                              void* d_out, int out_size, void* d_ws,
                              size_t ws_size, hipStream_t stream) {
    const float* x = (const float*)d_in[0];
    const float* Wq = (const float*)d_in[1];
    const float* Wk = (const float*)d_in[2];
    const float* Wv = (const float*)d_in[3];
    const float* Wo = (const float*)d_in[4];
    const int* tokpos = (const int*)d_in[5];
    float* out = (float*)d_out;

    const size_t MD = (size_t)MTOT * DMODEL;  // 4194304
    const size_t WD = (size_t)DMODEL * DMODEL;
    unsigned short* xb = (unsigned short*)d_ws;
    unsigned short* Wqt = xb + MD;
    unsigned short* Wkt = Wqt + WD;
    unsigned short* Wvt = Wkt + WD;
    unsigned short* Wot = Wvt + WD;
    unsigned short* Q = Wot + WD;
    unsigned short* K = Q + MD;
    unsigned short* V = K + MD;   // after vtrans, reused as attention output O
    unsigned short* Vt = V + MD;  // [b*1024 + d][s]
    float* ct = (float*)(Vt + MD);
    float* st = ct + S_LEN * 32;
    unsigned short* O = V;  // alias: V dead after vtrans_k

    rope_tables_k<<<dim3((S_LEN * 32) / 256), dim3(256), 0, stream>>>(tokpos, ct, st);
    cast_x_k<<<dim3(MD / 2048), dim3(256), 0, stream>>>(x, xb);
    trans_w_k<<<dim3(16, 16, 4), dim3(256), 0, stream>>>(Wq, Wk, Wv, Wo, Wqt, Wkt, Wvt, Wot);

    // Q,K (RoPE permuted-d bf16) and V (plain bf16)
    mm_k<<<dim3(8, 32, 3), dim3(256), 0, stream>>>(xb, Wqt, Wkt, Wvt,
                                                   (void*)Q, (void*)K, (void*)V, ct, st, 0);
    vtrans_k<<<dim3(64, 16), dim3(256), 0, stream>>>(V, Vt);
    attn_k<<<dim3(1024), dim3(256), 0, stream>>>(Q, K, Vt, O);
    // output projection, fp32 store
    mm_k<<<dim3(8, 32, 1), dim3(256), 0, stream>>>(O, Wot, Wot, Wot,
                                                   (void*)out, (void*)out, (void*)out, ct, st, 1);
}

// Round 6
// 222.334 us; speedup vs baseline: 6.9860x; 1.0074x over previous
//
#include <hip/hip_runtime.h>
#include <cmath>

#define S_LEN 2048
#define DMODEL 1024
#define NHEADS 16
#define DK 64
#define BATCH 2
#define MTOT (BATCH * S_LEN) /* 4096 */

using short8 = __attribute__((ext_vector_type(8))) short;
using floatx4 = __attribute__((ext_vector_type(4))) float;

// float -> bf16 bits, round-to-nearest-even
__device__ __forceinline__ unsigned short f2b(float f) {
    union { float f; unsigned u; } v; v.f = f;
    unsigned r = v.u + 0x7fff + ((v.u >> 16) & 1);
    return (unsigned short)(r >> 16);
}

// async global->LDS, 16 B/lane. LDS dest is wave-uniform base (+lane*16 by HW).
__device__ __forceinline__ void gload16(const void* g, void* l) {
    __builtin_amdgcn_global_load_lds(
        (const __attribute__((address_space(1))) unsigned int*)g,
        (__attribute__((address_space(3))) unsigned int*)l, 16, 0, 0);
}

// ---------------------------------------------------------------------------
// Fused preprocessing (single dispatch, blockIdx-range partition):
//   blocks [0, 2048)        : x fp32 -> bf16 cast
//   blocks [2048, 2304)     : RoPE cos/sin tables
//   blocks [2304, 3328)     : W fp32 [k][n] -> bf16 [n][k] transpose
//                             (Wq,Wk head-dims permuted: d -> d/2 or 32+d/2)
// ---------------------------------------------------------------------------
__global__ __launch_bounds__(256) void prep_k(
    const float* __restrict__ x, unsigned short* __restrict__ xb,
    const int* __restrict__ tokpos, float* __restrict__ ct, float* __restrict__ st,
    const float* W0, const float* W1, const float* W2, const float* W3,
    unsigned short* T0, unsigned short* T1, unsigned short* T2, unsigned short* T3) {
    __shared__ float t[64][65];
    const int b = blockIdx.x;
    if (b < 2048) {
        int i = (b * 256 + threadIdx.x) * 8;
        float4 a = *(const float4*)(x + i);
        float4 bb = *(const float4*)(x + i + 4);
        short8 o;
        o[0] = f2b(a.x); o[1] = f2b(a.y); o[2] = f2b(a.z); o[3] = f2b(a.w);
        o[4] = f2b(bb.x); o[5] = f2b(bb.y); o[6] = f2b(bb.z); o[7] = f2b(bb.w);
        *(short8*)(xb + i) = o;
    } else if (b < 2304) {
        int idx = (b - 2048) * 256 + threadIdx.x;  // 0 .. 2048*32-1
        int si = idx >> 5;
        int ip = idx & 31;
        float pos = (float)tokpos[si];
        float inv_freq = powf(10000.0f, -(float)(2 * ip) / 64.0f);
        float ang = pos * inv_freq;
        ct[idx] = cosf(ang);
        st[idx] = sinf(ang);
    } else {
        int id = b - 2304;          // 0..1023
        int z = id >> 8;            // matrix
        int bx = id & 15, by = (id >> 4) & 15;
        const float* W = z == 0 ? W0 : z == 1 ? W1 : z == 2 ? W2 : W3;
        unsigned short* T = z == 0 ? T0 : z == 1 ? T1 : z == 2 ? T2 : T3;
        const bool perm = (z < 2);
        int n0 = bx * 64, k0 = by * 64;
        int rr = threadIdx.x >> 6, cc = threadIdx.x & 63;
#pragma unroll
        for (int r = 0; r < 16; r++) {
            int row = r * 4 + rr;
            t[row][cc] = W[(size_t)(k0 + row) * DMODEL + n0 + cc];
        }
        __syncthreads();
#pragma unroll
        for (int r = 0; r < 16; r++) {
            int row = r * 4 + rr;  // original col within head
            int drow = perm ? (((row & 1) ? 32 : 0) + (row >> 1)) : row;
            T[(size_t)(n0 + drow) * DMODEL + k0 + cc] = f2b(t[cc][row]);
        }
    }
}

// ---------------------------------------------------------------------------
// V[s][d] bf16 -> Vt[b*1024 + d][s] bf16, 64x64 LDS tiles
// ---------------------------------------------------------------------------
__global__ __launch_bounds__(256) void vtrans_k(const unsigned short* __restrict__ V,
                                                unsigned short* __restrict__ Vt) {
    __shared__ unsigned short t[64][72];  // 144 B rows: 16B-aligned, bank-spread
    const int tid = threadIdx.x;
    const int s0 = blockIdx.x * 64, d0 = blockIdx.y * 64;
    const int bb = s0 >> 11;
#pragma unroll
    for (int it = 0; it < 4; it++) {
        int e = (it * 256 + tid) * 4;  // flat ushort4 id: row=s, col=d
        int r = e >> 6, c = e & 63;
        *(ushort4*)&t[r][c] = *(const ushort4*)(V + (size_t)(s0 + r) * DMODEL + d0 + c);
    }
    __syncthreads();
#pragma unroll
    for (int it = 0; it < 4; it++) {
        int e = (it * 256 + tid) * 4;  // flat ushort4 id: row=d, col=s
        int r = e >> 6, c = e & 63;
        ushort4 v;
        v.x = t[c + 0][r]; v.y = t[c + 1][r];
        v.z = t[c + 2][r]; v.w = t[c + 3][r];
        *(ushort4*)(Vt + (size_t)(bb * 1024 + d0 + r) * S_LEN + (s0 & (S_LEN - 1)) + c) = v;
    }
}

// ---------------------------------------------------------------------------
// bf16 MFMA GEMM: C[4096,1024] = A[4096,1024] x Bt^T  (Bt is [N][K] bf16)
// 128x128 tile, BK=64 (16 K-iterations: half the barriers of BK=32),
// 4 waves, 2 x 16 mfma 16x16x32 per wave per iteration. LDS 32 KB.
// kind 0: z<2 -> RoPE (permuted-d weights, shuffle-free) bf16; z==2 -> plain
// bf16 (V). kind 1: plain fp32 store (final output).
// ---------------------------------------------------------------------------
__global__ __launch_bounds__(256) void mm_k(
    const unsigned short* __restrict__ A,
    const unsigned short* __restrict__ Bt0, const unsigned short* __restrict__ Bt1,
    const unsigned short* __restrict__ Bt2,
    void* C0, void* C1, void* C2,
    const float* __restrict__ ct, const float* __restrict__ st, int kind) {
    // 32 KB: A groups 0..15 (16 KB), B groups 16..31 (16 KB).
    // A group g: rows (g&7)*16..+15, k-half (g>>3)*32; chunk = lane -> row l15,
    // k-sub quad*8. 1024 B per group.
    __shared__ __align__(16) unsigned short blob[16384];

    const int z = blockIdx.z;
    const unsigned short* Bt = z == 0 ? Bt0 : z == 1 ? Bt1 : Bt2;
    void* C = z == 0 ? C0 : z == 1 ? C1 : C2;
    const int mode = (kind == 1) ? 0 : (z == 2 ? 3 : 1);

    const int tid = threadIdx.x;
    const int w = tid >> 6, lane = tid & 63;
    const int l15 = lane & 15, quad = lane >> 4;
    const int wr = w >> 1, wc = w & 1;
    const int m0 = blockIdx.y * 128, n0 = blockIdx.x * 128;

    floatx4 acc[4][4];
#pragma unroll
    for (int i = 0; i < 4; i++)
#pragma unroll
        for (int j = 0; j < 4; j++) acc[i][j] = (floatx4){0.f, 0.f, 0.f, 0.f};

    for (int k0 = 0; k0 < DMODEL; k0 += 64) {
        if (k0) __syncthreads();
#pragma unroll
        for (int it = 0; it < 8; it++) {
            int g = it * 4 + w;  // wave-uniform group 0..31
            const unsigned short* gp;
            if (g < 16)
                gp = A + (size_t)(m0 + (g & 7) * 16 + l15) * DMODEL + k0 + (g >> 3) * 32 + quad * 8;
            else {
                int gb = g - 16;
                gp = Bt + (size_t)(n0 + (gb & 7) * 16 + l15) * DMODEL + k0 + (gb >> 3) * 32 + quad * 8;
            }
            gload16(gp, (char*)blob + g * 1024);
        }
        __syncthreads();

#pragma unroll
        for (int h = 0; h < 2; h++) {
            short8 af[4], bfr[4];
#pragma unroll
            for (int i = 0; i < 4; i++)
                af[i] = *(const short8*)((char*)blob + ((h * 8 + wr * 4 + i) * 64 + lane) * 16);
#pragma unroll
            for (int j = 0; j < 4; j++)
                bfr[j] = *(const short8*)((char*)blob + 16384 + ((h * 8 + wc * 4 + j) * 64 + lane) * 16);
#pragma unroll
            for (int i = 0; i < 4; i++)
#pragma unroll
                for (int j = 0; j < 4; j++)
                    acc[i][j] = __builtin_amdgcn_mfma_f32_16x16x32_bf16(af[i], bfr[j], acc[i][j], 0, 0, 0);
        }
    }

    // epilogue: C/D layout col = l15, row = quad*4 + reg
#pragma unroll
    for (int i = 0; i < 4; i++) {
        const int rowb = m0 + wr * 64 + i * 16 + quad * 4;
        if (mode == 0) {
            float* Cf = (float*)C;
#pragma unroll
            for (int j = 0; j < 4; j++) {
                int colb = n0 + wc * 64 + j * 16 + l15;
#pragma unroll
                for (int r = 0; r < 4; r++)
                    Cf[(size_t)(rowb + r) * DMODEL + colb] = acc[i][j][r];
            }
        } else if (mode == 1) {
            unsigned short* Cb = (unsigned short*)C;
#pragma unroll
            for (int jh = 0; jh < 2; jh++) {
                int ip = jh * 16 + l15;                   // pair index within head
                int cole = n0 + wc * 64 + jh * 16 + l15;  // even-member column (d'<32)
#pragma unroll
                for (int r = 0; r < 4; r++) {
                    int row = rowb + r;
                    int si = row & (S_LEN - 1);
                    float c = ct[si * 32 + ip];
                    float s = st[si * 32 + ip];
                    float e = acc[i][jh][r];       // x_even (permuted weights)
                    float od = acc[i][jh + 2][r];  // x_odd (partner col, same thread)
                    Cb[(size_t)row * DMODEL + cole] = f2b(e * c - od * s);
                    Cb[(size_t)row * DMODEL + cole + 32] = f2b(e * s + od * c);
                }
            }
        } else {
            unsigned short* Cb = (unsigned short*)C;
#pragma unroll
            for (int j = 0; j < 4; j++) {
                int colb = n0 + wc * 64 + j * 16 + l15;
#pragma unroll
                for (int r = 0; r < 4; r++)
                    Cb[(size_t)(rowb + r) * DMODEL + colb] = f2b(acc[i][j][r]);
            }
        }
    }
}

// ---------------------------------------------------------------------------
// Block-cooperative MFMA flash attention, 64-key tiles, 128-query blocks.
// Grid 512 = (16 q-tiles x 32 bh), longest first; 8 waves (512 thr), each
// wave owns 16 queries. One staged K/V tile feeds 8 waves (2x the R5
// amortization; total staged tiles/bh 528 -> 272). Double-buffered LDS via
// global_load_lds, 1 barrier per tile. S^T = K Q^T -> per-lane softmax
// (2 shfl for max, l deferred), P via per-wave LDS -> O^T = V^T P^T.
// ---------------------------------------------------------------------------
__global__ __launch_bounds__(512) void attn_k(const unsigned short* __restrict__ Q,
                                              const unsigned short* __restrict__ K,
                                              const unsigned short* __restrict__ Vt,
                                              unsigned short* __restrict__ O) {
    __shared__ __align__(16) unsigned short Kblob[2][4096];  // 8 KB/buf
    __shared__ __align__(16) unsigned short Vblob[2][4096];
    __shared__ __align__(16) unsigned short Ps[8][16 * 72];  // per-wave P / O-bounce

    const int tid = threadIdx.x;
    const int w = tid >> 6, lane = tid & 63;
    const int l15 = lane & 15, quad = lane >> 4;
    const int idx = blockIdx.x;
    const int qt = 15 - (idx >> 5);  // longest blocks dispatch first
    const int bh = idx & 31;
    const int bb = bh >> 4, h = bh & 15;
    const int qbase = qt * 128 + w * 16;
    const int qrow = qbase + l15;

    // Q fragment (B-operand: col=query=l15, k=quad*8), d-halves 0/1
    const size_t qoff = (size_t)(bb * S_LEN + qbase + l15) * DMODEL + h * DK;
    short8 aq0 = *(const short8*)(Q + qoff + quad * 8);
    short8 aq1 = *(const short8*)(Q + qoff + 32 + quad * 8);

    floatx4 o[4];
#pragma unroll
    for (int f = 0; f < 4; f++) o[f] = (floatx4){0.f, 0.f, 0.f, 0.f};
    float mv = -1e30f, lv = 0.f;

    const unsigned short* Kb = K + (size_t)(bb * S_LEN) * DMODEL + h * DK;
    const unsigned short* Vb = Vt + (size_t)(bb * 1024 + h * DK) * S_LEN;
    unsigned short* ps = &Ps[w][0];

    // stage 64-key K/V tile into blob buffer b (2 gload16/thread, 8 waves)
    auto stage = [&](int b, int kb) {
#pragma unroll
        for (int it = 0; it < 2; it++) {
            int g = it * 8 + w;  // wave-uniform 0..15; 0..7 K-groups, 8..15 V-groups
            if (g < 8) {
                const unsigned short* gp =
                    Kb + (size_t)(kb + (g >> 1) * 16 + l15) * DMODEL + (g & 1) * 32 + quad * 8;
                gload16(gp, (char*)&Kblob[b][0] + g * 1024);
            } else {
                int gv = g - 8;
                const unsigned short* gp =
                    Vb + (size_t)((gv >> 1) * 16 + l15) * S_LEN + kb + (gv & 1) * 32 + quad * 8;
                gload16(gp, (char*)&Vblob[b][0] + gv * 1024);
            }
        }
    };

    const int nkt = 2 * qt + 2;  // key tiles covering 0..qt*128+127, uniform
    stage(0, 0);
    for (int kt = 0; kt < nkt; kt++) {
        const int b = kt & 1;
        const int kb = kt * 64;
        __syncthreads();  // staging of buf b complete; buf b^1 reads done
        if (kt + 1 < nkt) stage(b ^ 1, (kt + 1) * 64);

        // QK^T: S^T[key 64][q 16]
        const unsigned short* kbb = &Kblob[b][0];
        floatx4 c[4];
#pragma unroll
        for (int g = 0; g < 4; g++) {
            short8 kf0 = *(const short8*)(kbb + (g * 2 + 0) * 512 + lane * 8);
            short8 kf1 = *(const short8*)(kbb + (g * 2 + 1) * 512 + lane * 8);
            floatx4 t = {0.f, 0.f, 0.f, 0.f};
            t = __builtin_amdgcn_mfma_f32_16x16x32_bf16(kf0, aq0, t, 0, 0, 0);
            c[g] = __builtin_amdgcn_mfma_f32_16x16x32_bf16(kf1, aq1, t, 0, 0, 0);
        }

        // softmax over 16 keys/lane (keys kb + g*16 + quad*4 + r)
        float sv[16];
#pragma unroll
        for (int g = 0; g < 4; g++)
#pragma unroll
            for (int r = 0; r < 4; r++) {
                int key = kb + g * 16 + quad * 4 + r;
                sv[g * 4 + r] = (key <= qrow) ? c[g][r] * 0.125f : -1e30f;
            }
        float mx = sv[0];
#pragma unroll
        for (int i = 1; i < 16; i++) mx = fmaxf(mx, sv[i]);
        mx = fmaxf(mx, __shfl_xor(mx, 16));
        mx = fmaxf(mx, __shfl_xor(mx, 32));
        float mnew = fmaxf(mv, mx);
        float alpha = __expf(mv - mnew);
        mv = mnew;
        float p[16], psum = 0.f;
#pragma unroll
        for (int i = 0; i < 16; i++) {
            p[i] = __expf(sv[i] - mnew);
            psum += p[i];
        }
        lv = lv * alpha + psum;  // per-lane partial; cross-quad reduce at end

        // P -> LDS (row=q l15, key = g*16+quad*4..+3), stride 72 shorts
#pragma unroll
        for (int g = 0; g < 4; g++) {
            ushort4 pk;
            pk.x = f2b(p[g * 4 + 0]); pk.y = f2b(p[g * 4 + 1]);
            pk.z = f2b(p[g * 4 + 2]); pk.w = f2b(p[g * 4 + 3]);
            *(ushort4*)(ps + l15 * 72 + g * 16 + quad * 4) = pk;
        }
#pragma unroll
        for (int f = 0; f < 4; f++) {
            o[f][0] *= alpha; o[f][1] *= alpha;
            o[f][2] *= alpha; o[f][3] *= alpha;
        }
        // P^T B-frags (col=q l15, keys quad*8 / +32)
        short8 pf0 = *(const short8*)(ps + l15 * 72 + quad * 8);
        short8 pf1 = *(const short8*)(ps + l15 * 72 + 32 + quad * 8);
        const unsigned short* vbb = &Vblob[b][0];
#pragma unroll
        for (int f = 0; f < 4; f++) {
            short8 vf0 = *(const short8*)(vbb + (f * 2 + 0) * 512 + lane * 8);
            short8 vf1 = *(const short8*)(vbb + (f * 2 + 1) * 512 + lane * 8);
            o[f] = __builtin_amdgcn_mfma_f32_16x16x32_bf16(vf0, pf0, o[f], 0, 0, 0);
            o[f] = __builtin_amdgcn_mfma_f32_16x16x32_bf16(vf1, pf1, o[f], 0, 0, 0);
        }
    }

    // final l reduction across quads, then un-transpose O^T via LDS
    lv += __shfl_xor(lv, 16);
    lv += __shfl_xor(lv, 32);
    float inv = 1.0f / lv;
    __syncthreads();  // safe reuse of Ps region
#pragma unroll
    for (int f = 0; f < 4; f++) {
        ushort4 pk;
        pk.x = f2b(o[f][0] * inv);
        pk.y = f2b(o[f][1] * inv);
        pk.z = f2b(o[f][2] * inv);
        pk.w = f2b(o[f][3] * inv);
        *(ushort4*)(ps + l15 * 72 + f * 16 + quad * 4) = pk;  // row=q, d=f*16+quad*4
    }
    short8 r0 = *(const short8*)(ps + l15 * 72 + quad * 8);
    short8 r1 = *(const short8*)(ps + l15 * 72 + 32 + quad * 8);
    size_t obase = (size_t)(bb * S_LEN + qbase + l15) * DMODEL + h * DK;
    *(short8*)(O + obase + quad * 8) = r0;
    *(short8*)(O + obase + 32 + quad * 8) = r1;
}

// ---------------------------------------------------------------------------
extern "C" void kernel_launch(void* const* d_in, const int* in_sizes, int n_in,
                              void* d_out, int out_size, void* d_ws,
                              size_t ws_size, hipStream_t stream) {
    const float* x = (const float*)d_in[0];
    const float* Wq = (const float*)d_in[1];
    const float* Wk = (const float*)d_in[2];
    const float* Wv = (const float*)d_in[3];
    const float* Wo = (const float*)d_in[4];
    const int* tokpos = (const int*)d_in[5];
    float* out = (float*)d_out;

    const size_t MD = (size_t)MTOT * DMODEL;  // 4194304
    const size_t WD = (size_t)DMODEL * DMODEL;
    unsigned short* xb = (unsigned short*)d_ws;
    unsigned short* Wqt = xb + MD;
    unsigned short* Wkt = Wqt + WD;
    unsigned short* Wvt = Wkt + WD;
    unsigned short* Wot = Wvt + WD;
    unsigned short* Q = Wot + WD;
    unsigned short* K = Q + MD;
    unsigned short* V = K + MD;   // after vtrans, reused as attention output O
    unsigned short* Vt = V + MD;  // [b*1024 + d][s]
    float* ct = (float*)(Vt + MD);
    float* st = ct + S_LEN * 32;
    unsigned short* O = V;  // alias: V dead after vtrans_k

    // fused preprocessing: cast + rope tables + weight transposes
    prep_k<<<dim3(3328), dim3(256), 0, stream>>>(x, xb, tokpos, ct, st,
                                                 Wq, Wk, Wv, Wo, Wqt, Wkt, Wvt, Wot);

    // Q,K (RoPE permuted-d bf16) and V (plain bf16)
    mm_k<<<dim3(8, 32, 3), dim3(256), 0, stream>>>(xb, Wqt, Wkt, Wvt,
                                                   (void*)Q, (void*)K, (void*)V, ct, st, 0);
    vtrans_k<<<dim3(64, 16), dim3(256), 0, stream>>>(V, Vt);
    attn_k<<<dim3(512), dim3(512), 0, stream>>>(Q, K, Vt, O);
    // output projection, fp32 store
    mm_k<<<dim3(8, 32, 1), dim3(256), 0, stream>>>(O, Wot, Wot, Wot,
                                                   (void*)out, (void*)out, (void*)out, ct, st, 1);
}

// Round 7
// 218.611 us; speedup vs baseline: 7.1050x; 1.0170x over previous
//
#include <hip/hip_runtime.h>
#include <cmath>

#define S_LEN 2048
#define DMODEL 1024
#define NHEADS 16
#define DK 64
#define BATCH 2
#define MTOT (BATCH * S_LEN) /* 4096 */

using short8 = __attribute__((ext_vector_type(8))) short;
using floatx4 = __attribute__((ext_vector_type(4))) float;

// float -> bf16 bits, round-to-nearest-even
__device__ __forceinline__ unsigned short f2b(float f) {
    union { float f; unsigned u; } v; v.f = f;
    unsigned r = v.u + 0x7fff + ((v.u >> 16) & 1);
    return (unsigned short)(r >> 16);
}

// async global->LDS, 16 B/lane. LDS dest is wave-uniform base (+lane*16 by HW).
__device__ __forceinline__ void gload16(const void* g, void* l) {
    __builtin_amdgcn_global_load_lds(
        (const __attribute__((address_space(1))) unsigned int*)g,
        (__attribute__((address_space(3))) unsigned int*)l, 16, 0, 0);
}

// ---------------------------------------------------------------------------
// Fused preprocessing (single dispatch, blockIdx-range partition):
//   blocks [0, 2048)        : x fp32 -> bf16 cast
//   blocks [2048, 2304)     : RoPE cos/sin tables
//   blocks [2304, 3328)     : W fp32 [k][n] -> bf16 [n][k] transpose
//                             (Wq,Wk head-dims permuted: d -> d/2 or 32+d/2)
// ---------------------------------------------------------------------------
__global__ __launch_bounds__(256) void prep_k(
    const float* __restrict__ x, unsigned short* __restrict__ xb,
    const int* __restrict__ tokpos, float* __restrict__ ct, float* __restrict__ st,
    const float* W0, const float* W1, const float* W2, const float* W3,
    unsigned short* T0, unsigned short* T1, unsigned short* T2, unsigned short* T3) {
    __shared__ float t[64][65];
    const int b = blockIdx.x;
    if (b < 2048) {
        int i = (b * 256 + threadIdx.x) * 8;
        float4 a = *(const float4*)(x + i);
        float4 bb = *(const float4*)(x + i + 4);
        short8 o;
        o[0] = f2b(a.x); o[1] = f2b(a.y); o[2] = f2b(a.z); o[3] = f2b(a.w);
        o[4] = f2b(bb.x); o[5] = f2b(bb.y); o[6] = f2b(bb.z); o[7] = f2b(bb.w);
        *(short8*)(xb + i) = o;
    } else if (b < 2304) {
        int idx = (b - 2048) * 256 + threadIdx.x;  // 0 .. 2048*32-1
        int si = idx >> 5;
        int ip = idx & 31;
        float pos = (float)tokpos[si];
        float inv_freq = powf(10000.0f, -(float)(2 * ip) / 64.0f);
        float ang = pos * inv_freq;
        ct[idx] = cosf(ang);
        st[idx] = sinf(ang);
    } else {
        int id = b - 2304;          // 0..1023
        int z = id >> 8;            // matrix
        int bx = id & 15, by = (id >> 4) & 15;
        const float* W = z == 0 ? W0 : z == 1 ? W1 : z == 2 ? W2 : W3;
        unsigned short* T = z == 0 ? T0 : z == 1 ? T1 : z == 2 ? T2 : T3;
        const bool perm = (z < 2);
        int n0 = bx * 64, k0 = by * 64;
        int rr = threadIdx.x >> 6, cc = threadIdx.x & 63;
#pragma unroll
        for (int r = 0; r < 16; r++) {
            int row = r * 4 + rr;
            t[row][cc] = W[(size_t)(k0 + row) * DMODEL + n0 + cc];
        }
        __syncthreads();
#pragma unroll
        for (int r = 0; r < 16; r++) {
            int row = r * 4 + rr;  // original col within head
            int drow = perm ? (((row & 1) ? 32 : 0) + (row >> 1)) : row;
            T[(size_t)(n0 + drow) * DMODEL + k0 + cc] = f2b(t[cc][row]);
        }
    }
}

// ---------------------------------------------------------------------------
// V[s][d] bf16 -> Vt[b*1024 + d][s] bf16, 64x64 LDS tiles
// ---------------------------------------------------------------------------
__global__ __launch_bounds__(256) void vtrans_k(const unsigned short* __restrict__ V,
                                                unsigned short* __restrict__ Vt) {
    __shared__ unsigned short t[64][72];  // 144 B rows: 16B-aligned, bank-spread
    const int tid = threadIdx.x;
    const int s0 = blockIdx.x * 64, d0 = blockIdx.y * 64;
    const int bb = s0 >> 11;
#pragma unroll
    for (int it = 0; it < 4; it++) {
        int e = (it * 256 + tid) * 4;  // flat ushort4 id: row=s, col=d
        int r = e >> 6, c = e & 63;
        *(ushort4*)&t[r][c] = *(const ushort4*)(V + (size_t)(s0 + r) * DMODEL + d0 + c);
    }
    __syncthreads();
#pragma unroll
    for (int it = 0; it < 4; it++) {
        int e = (it * 256 + tid) * 4;  // flat ushort4 id: row=d, col=s
        int r = e >> 6, c = e & 63;
        ushort4 v;
        v.x = t[c + 0][r]; v.y = t[c + 1][r];
        v.z = t[c + 2][r]; v.w = t[c + 3][r];
        *(ushort4*)(Vt + (size_t)(bb * 1024 + d0 + r) * S_LEN + (s0 & (S_LEN - 1)) + c) = v;
    }
}

// ---------------------------------------------------------------------------
// bf16 MFMA GEMM: C[4096,1024] = A[4096,1024] x Bt^T  (Bt is [N][K] bf16)
// 128x128 tile, BK=32 (R5 config — BK=64 regressed), 4 waves, 4x4 mfma.
// Grid (x=m 32, y=n 8, z=matrix): blocks sharing an A-tile (same x; y,z vary
// with linear strides 32/256, both =0 mod 8) land on the SAME XCD, so each
// A-tile is fetched into exactly one L2 -> FETCH_SIZE drop.
// kind 0: z<2 -> RoPE (permuted-d weights, shuffle-free) bf16; z==2 -> plain
// bf16 (V). kind 1: plain fp32 store (final output).
// ---------------------------------------------------------------------------
__global__ __launch_bounds__(256) void mm_k(
    const unsigned short* __restrict__ A,
    const unsigned short* __restrict__ Bt0, const unsigned short* __restrict__ Bt1,
    const unsigned short* __restrict__ Bt2,
    void* C0, void* C1, void* C2,
    const float* __restrict__ ct, const float* __restrict__ st, int kind) {
    __shared__ __align__(16) unsigned short blob[8192];  // 16 KB: A 8K + B 8K bytes

    const int z = blockIdx.z;
    const unsigned short* Bt = z == 0 ? Bt0 : z == 1 ? Bt1 : Bt2;
    void* C = z == 0 ? C0 : z == 1 ? C1 : C2;
    const int mode = (kind == 1) ? 0 : (z == 2 ? 3 : 1);

    const int tid = threadIdx.x;
    const int w = tid >> 6, lane = tid & 63;
    const int l15 = lane & 15, quad = lane >> 4;
    const int wr = w >> 1, wc = w & 1;
    const int m0 = blockIdx.x * 128, n0 = blockIdx.y * 128;  // x=m: XCD A-reuse

    floatx4 acc[4][4];
#pragma unroll
    for (int i = 0; i < 4; i++)
#pragma unroll
        for (int j = 0; j < 4; j++) acc[i][j] = (floatx4){0.f, 0.f, 0.f, 0.f};

    for (int k0 = 0; k0 < DMODEL; k0 += 32) {
        if (k0) __syncthreads();
#pragma unroll
        for (int it = 0; it < 4; it++) {
            int g = it * 4 + w;  // wave-uniform group 0..15 (A: 0..7, B: 8..15)
            const unsigned short* gp;
            if (g < 8)
                gp = A + (size_t)(m0 + g * 16 + l15) * DMODEL + k0 + (lane >> 4) * 8;
            else
                gp = Bt + (size_t)(n0 + (g - 8) * 16 + l15) * DMODEL + k0 + (lane >> 4) * 8;
            gload16(gp, (char*)blob + g * 1024);
        }
        __syncthreads();

        short8 af[4], bfr[4];
#pragma unroll
        for (int i = 0; i < 4; i++)
            af[i] = *(const short8*)((char*)blob + ((wr * 4 + i) * 64 + lane) * 16);
#pragma unroll
        for (int j = 0; j < 4; j++)
            bfr[j] = *(const short8*)((char*)blob + 8192 + ((wc * 4 + j) * 64 + lane) * 16);
#pragma unroll
        for (int i = 0; i < 4; i++)
#pragma unroll
            for (int j = 0; j < 4; j++)
                acc[i][j] = __builtin_amdgcn_mfma_f32_16x16x32_bf16(af[i], bfr[j], acc[i][j], 0, 0, 0);
    }

    // epilogue: C/D layout col = l15, row = quad*4 + reg
#pragma unroll
    for (int i = 0; i < 4; i++) {
        const int rowb = m0 + wr * 64 + i * 16 + quad * 4;
        if (mode == 0) {
            float* Cf = (float*)C;
#pragma unroll
            for (int j = 0; j < 4; j++) {
                int colb = n0 + wc * 64 + j * 16 + l15;
#pragma unroll
                for (int r = 0; r < 4; r++)
                    Cf[(size_t)(rowb + r) * DMODEL + colb] = acc[i][j][r];
            }
        } else if (mode == 1) {
            unsigned short* Cb = (unsigned short*)C;
#pragma unroll
            for (int jh = 0; jh < 2; jh++) {
                int ip = jh * 16 + l15;                   // pair index within head
                int cole = n0 + wc * 64 + jh * 16 + l15;  // even-member column (d'<32)
#pragma unroll
                for (int r = 0; r < 4; r++) {
                    int row = rowb + r;
                    int si = row & (S_LEN - 1);
                    float c = ct[si * 32 + ip];
                    float s = st[si * 32 + ip];
                    float e = acc[i][jh][r];       // x_even (permuted weights)
                    float od = acc[i][jh + 2][r];  // x_odd (partner col, same thread)
                    Cb[(size_t)row * DMODEL + cole] = f2b(e * c - od * s);
                    Cb[(size_t)row * DMODEL + cole + 32] = f2b(e * s + od * c);
                }
            }
        } else {
            unsigned short* Cb = (unsigned short*)C;
#pragma unroll
            for (int j = 0; j < 4; j++) {
                int colb = n0 + wc * 64 + j * 16 + l15;
#pragma unroll
                for (int r = 0; r < 4; r++)
                    Cb[(size_t)(rowb + r) * DMODEL + colb] = f2b(acc[i][j][r]);
            }
        }
    }
}

// ---------------------------------------------------------------------------
// Block-cooperative MFMA flash attention, 64-key tiles, 128-query blocks.
// Grid 512 = (16 q-tiles x 32 bh), longest first; 8 waves (512 thr), each
// wave owns 16 queries. One staged K/V tile feeds 8 waves. Double-buffered
// LDS via global_load_lds, 1 barrier per tile. S^T = K Q^T -> per-lane
// softmax (2 shfl for max, l deferred), P via per-wave LDS -> O^T = V^T P^T.
// ---------------------------------------------------------------------------
__global__ __launch_bounds__(512) void attn_k(const unsigned short* __restrict__ Q,
                                              const unsigned short* __restrict__ K,
                                              const unsigned short* __restrict__ Vt,
                                              unsigned short* __restrict__ O) {
    __shared__ __align__(16) unsigned short Kblob[2][4096];  // 8 KB/buf
    __shared__ __align__(16) unsigned short Vblob[2][4096];
    __shared__ __align__(16) unsigned short Ps[8][16 * 72];  // per-wave P / O-bounce

    const int tid = threadIdx.x;
    const int w = tid >> 6, lane = tid & 63;
    const int l15 = lane & 15, quad = lane >> 4;
    const int idx = blockIdx.x;
    const int qt = 15 - (idx >> 5);  // longest blocks dispatch first
    const int bh = idx & 31;
    const int bb = bh >> 4, h = bh & 15;
    const int qbase = qt * 128 + w * 16;
    const int qrow = qbase + l15;

    // Q fragment (B-operand: col=query=l15, k=quad*8), d-halves 0/1
    const size_t qoff = (size_t)(bb * S_LEN + qbase + l15) * DMODEL + h * DK;
    short8 aq0 = *(const short8*)(Q + qoff + quad * 8);
    short8 aq1 = *(const short8*)(Q + qoff + 32 + quad * 8);

    floatx4 o[4];
#pragma unroll
    for (int f = 0; f < 4; f++) o[f] = (floatx4){0.f, 0.f, 0.f, 0.f};
    float mv = -1e30f, lv = 0.f;

    const unsigned short* Kb = K + (size_t)(bb * S_LEN) * DMODEL + h * DK;
    const unsigned short* Vb = Vt + (size_t)(bb * 1024 + h * DK) * S_LEN;
    unsigned short* ps = &Ps[w][0];

    // stage 64-key K/V tile into blob buffer b (2 gload16/thread, 8 waves)
    auto stage = [&](int b, int kb) {
#pragma unroll
        for (int it = 0; it < 2; it++) {
            int g = it * 8 + w;  // wave-uniform 0..15; 0..7 K-groups, 8..15 V-groups
            if (g < 8) {
                const unsigned short* gp =
                    Kb + (size_t)(kb + (g >> 1) * 16 + l15) * DMODEL + (g & 1) * 32 + quad * 8;
                gload16(gp, (char*)&Kblob[b][0] + g * 1024);
            } else {
                int gv = g - 8;
                const unsigned short* gp =
                    Vb + (size_t)((gv >> 1) * 16 + l15) * S_LEN + kb + (gv & 1) * 32 + quad * 8;
                gload16(gp, (char*)&Vblob[b][0] + gv * 1024);
            }
        }
    };

    const int nkt = 2 * qt + 2;  // key tiles covering 0..qt*128+127, uniform
    stage(0, 0);
    for (int kt = 0; kt < nkt; kt++) {
        const int b = kt & 1;
        const int kb = kt * 64;
        __syncthreads();  // staging of buf b complete; buf b^1 reads done
        if (kt + 1 < nkt) stage(b ^ 1, (kt + 1) * 64);

        // QK^T: S^T[key 64][q 16]
        const unsigned short* kbb = &Kblob[b][0];
        floatx4 c[4];
#pragma unroll
        for (int g = 0; g < 4; g++) {
            short8 kf0 = *(const short8*)(kbb + (g * 2 + 0) * 512 + lane * 8);
            short8 kf1 = *(const short8*)(kbb + (g * 2 + 1) * 512 + lane * 8);
            floatx4 t = {0.f, 0.f, 0.f, 0.f};
            t = __builtin_amdgcn_mfma_f32_16x16x32_bf16(kf0, aq0, t, 0, 0, 0);
            c[g] = __builtin_amdgcn_mfma_f32_16x16x32_bf16(kf1, aq1, t, 0, 0, 0);
        }

        // softmax over 16 keys/lane (keys kb + g*16 + quad*4 + r)
        float sv[16];
#pragma unroll
        for (int g = 0; g < 4; g++)
#pragma unroll
            for (int r = 0; r < 4; r++) {
                int key = kb + g * 16 + quad * 4 + r;
                sv[g * 4 + r] = (key <= qrow) ? c[g][r] * 0.125f : -1e30f;
            }
        float mx = sv[0];
#pragma unroll
        for (int i = 1; i < 16; i++) mx = fmaxf(mx, sv[i]);
        mx = fmaxf(mx, __shfl_xor(mx, 16));
        mx = fmaxf(mx, __shfl_xor(mx, 32));
        float mnew = fmaxf(mv, mx);
        float alpha = __expf(mv - mnew);
        mv = mnew;
        float p[16], psum = 0.f;
#pragma unroll
        for (int i = 0; i < 16; i++) {
            p[i] = __expf(sv[i] - mnew);
            psum += p[i];
        }
        lv = lv * alpha + psum;  // per-lane partial; cross-quad reduce at end

        // P -> LDS (row=q l15, key = g*16+quad*4..+3), stride 72 shorts
#pragma unroll
        for (int g = 0; g < 4; g++) {
            ushort4 pk;
            pk.x = f2b(p[g * 4 + 0]); pk.y = f2b(p[g * 4 + 1]);
            pk.z = f2b(p[g * 4 + 2]); pk.w = f2b(p[g * 4 + 3]);
            *(ushort4*)(ps + l15 * 72 + g * 16 + quad * 4) = pk;
        }
#pragma unroll
        for (int f = 0; f < 4; f++) {
            o[f][0] *= alpha; o[f][1] *= alpha;
            o[f][2] *= alpha; o[f][3] *= alpha;
        }
        // P^T B-frags (col=q l15, keys quad*8 / +32)
        short8 pf0 = *(const short8*)(ps + l15 * 72 + quad * 8);
        short8 pf1 = *(const short8*)(ps + l15 * 72 + 32 + quad * 8);
        const unsigned short* vbb = &Vblob[b][0];
#pragma unroll
        for (int f = 0; f < 4; f++) {
            short8 vf0 = *(const short8*)(vbb + (f * 2 + 0) * 512 + lane * 8);
            short8 vf1 = *(const short8*)(vbb + (f * 2 + 1) * 512 + lane * 8);
            o[f] = __builtin_amdgcn_mfma_f32_16x16x32_bf16(vf0, pf0, o[f], 0, 0, 0);
            o[f] = __builtin_amdgcn_mfma_f32_16x16x32_bf16(vf1, pf1, o[f], 0, 0, 0);
        }
    }

    // final l reduction across quads, then un-transpose O^T via LDS
    lv += __shfl_xor(lv, 16);
    lv += __shfl_xor(lv, 32);
    float inv = 1.0f / lv;
    __syncthreads();  // safe reuse of Ps region
#pragma unroll
    for (int f = 0; f < 4; f++) {
        ushort4 pk;
        pk.x = f2b(o[f][0] * inv);
        pk.y = f2b(o[f][1] * inv);
        pk.z = f2b(o[f][2] * inv);
        pk.w = f2b(o[f][3] * inv);
        *(ushort4*)(ps + l15 * 72 + f * 16 + quad * 4) = pk;  // row=q, d=f*16+quad*4
    }
    short8 r0 = *(const short8*)(ps + l15 * 72 + quad * 8);
    short8 r1 = *(const short8*)(ps + l15 * 72 + 32 + quad * 8);
    size_t obase = (size_t)(bb * S_LEN + qbase + l15) * DMODEL + h * DK;
    *(short8*)(O + obase + quad * 8) = r0;
    *(short8*)(O + obase + 32 + quad * 8) = r1;
}

// ---------------------------------------------------------------------------
extern "C" void kernel_launch(void* const* d_in, const int* in_sizes, int n_in,
                              void* d_out, int out_size, void* d_ws,
                              size_t ws_size, hipStream_t stream) {
    const float* x = (const float*)d_in[0];
    const float* Wq = (const float*)d_in[1];
    const float* Wk = (const float*)d_in[2];
    const float* Wv = (const float*)d_in[3];
    const float* Wo = (const float*)d_in[4];
    const int* tokpos = (const int*)d_in[5];
    float* out = (float*)d_out;

    const size_t MD = (size_t)MTOT * DMODEL;  // 4194304
    const size_t WD = (size_t)DMODEL * DMODEL;
    unsigned short* xb = (unsigned short*)d_ws;
    unsigned short* Wqt = xb + MD;
    unsigned short* Wkt = Wqt + WD;
    unsigned short* Wvt = Wkt + WD;
    unsigned short* Wot = Wvt + WD;
    unsigned short* Q = Wot + WD;
    unsigned short* K = Q + MD;
    unsigned short* V = K + MD;   // after vtrans, reused as attention output O
    unsigned short* Vt = V + MD;  // [b*1024 + d][s]
    float* ct = (float*)(Vt + MD);
    float* st = ct + S_LEN * 32;
    unsigned short* O = V;  // alias: V dead after vtrans_k

    // fused preprocessing: cast + rope tables + weight transposes
    prep_k<<<dim3(3328), dim3(256), 0, stream>>>(x, xb, tokpos, ct, st,
                                                 Wq, Wk, Wv, Wo, Wqt, Wkt, Wvt, Wot);

    // Q,K (RoPE permuted-d bf16) and V (plain bf16); grid x=m for XCD A-reuse
    mm_k<<<dim3(32, 8, 3), dim3(256), 0, stream>>>(xb, Wqt, Wkt, Wvt,
                                                   (void*)Q, (void*)K, (void*)V, ct, st, 0);
    vtrans_k<<<dim3(64, 16), dim3(256), 0, stream>>>(V, Vt);
    attn_k<<<dim3(512), dim3(512), 0, stream>>>(Q, K, Vt, O);
    // output projection, fp32 store
    mm_k<<<dim3(32, 8, 1), dim3(256), 0, stream>>>(O, Wot, Wot, Wot,
                                                   (void*)out, (void*)out, (void*)out, ct, st, 1);
}